// Round 4
// baseline (257.161 us; speedup 1.0000x reference)
//
#include <hip/hip_runtime.h>
#include <stdint.h>

#define D 128
#define EPB 1024   // edges per hist/scat block

typedef __bf16 bf16x8 __attribute__((ext_vector_type(8)));
typedef float f32x4 __attribute__((ext_vector_type(4)));

__device__ inline float bf2f(unsigned short u) {
    return __uint_as_float((unsigned)u << 16);
}
__device__ inline unsigned short f2bf(float f) {
    unsigned u = __float_as_uint(f);
    return (unsigned short)((u + 0x7FFF + ((u >> 16) & 1)) >> 16);  // RNE
}

struct Params {
    const float* x; const int* ei; const float* ew;
    const float* W1; const float* b1; const float* W2; const float* b2;
    float* out;
    int N, E, hbn, gb, hb, sn;   // hbn = hist/scat blocks, sn = node-scan blocks
    unsigned short *Wt1, *Wt2;
    unsigned long long* cntdeg;  // [N] packed: count<<40 | deg_fixpoint(2^24)
    unsigned int* cur;           // [N] scatter cursors
    int* lbase;                  // [N] block-local exclusive prefix of cnt
    int* cnt;                    // [N]
    float* dinv;                 // [N]
    int* bsum; int* bpref;       // [sn] block sums / exclusive prefix
    int2* erec;                  // [E] (src, ew) grouped by dst
    unsigned short *Hbuf, *Abuf;
};

// ================= phase bodies =================

__device__ inline void dev_prep(int which, const Params& p) {
    const float* W = (which == 0) ? p.W1 : p.W2;
    unsigned short* Wt = (which == 0) ? p.Wt1 : p.Wt2;
    for (int i = threadIdx.x; i < 2048; i += 256) {
        int nn = i >> 4;
        int kc = (i & 15) << 3;
        ushort4 o0, o1;
        o0.x = f2bf(W[(kc + 0) * 128 + nn]); o0.y = f2bf(W[(kc + 1) * 128 + nn]);
        o0.z = f2bf(W[(kc + 2) * 128 + nn]); o0.w = f2bf(W[(kc + 3) * 128 + nn]);
        o1.x = f2bf(W[(kc + 4) * 128 + nn]); o1.y = f2bf(W[(kc + 5) * 128 + nn]);
        o1.z = f2bf(W[(kc + 6) * 128 + nn]); o1.w = f2bf(W[(kc + 7) * 128 + nn]);
        *(ushort4*)(Wt + nn * 128 + kc) = o0;
        *(ushort4*)(Wt + nn * 128 + kc + 4) = o1;
    }
}

// one packed 64-bit atomic per edge: count (hi 24b) + fixed-point degree (lo 40b)
__device__ inline void dev_hist(int b, const Params& p) {
    const int base = b * EPB + threadIdx.x;
#pragma unroll
    for (int k = 0; k < EPB / 256; ++k) {
        int e = base + k * 256;
        if (e < p.E) {
            unsigned d = (unsigned)p.ei[p.E + e];
            unsigned long long pk =
                (1ULL << 40) | (unsigned long long)(unsigned)(p.ew[e] * 16777216.0f);
            atomicAdd(&p.cntdeg[d], pk);
        }
    }
}

// per-256-node-block exclusive scan of counts; also unpacks cnt/dinv
__device__ inline void dev_scanL(int b, const Params& p, int* tmp) {
    const int tid = threadIdx.x;
    const int n = b * 256 + tid;
    int c = 0;
    if (n < p.N) {
        unsigned long long v = p.cntdeg[n];
        c = (int)(v >> 40);
        float deg = 1.0f + (float)(v & 0xFFFFFFFFFFULL) * (1.0f / 16777216.0f);
        p.dinv[n] = rsqrtf(deg);
        p.cnt[n] = c;
    }
    tmp[tid] = c;
    __syncthreads();
    for (int off = 1; off < 256; off <<= 1) {
        int t = (tid >= off) ? tmp[tid - off] : 0;
        __syncthreads();
        tmp[tid] += t;
        __syncthreads();
    }
    if (n < p.N) p.lbase[n] = tmp[tid] - c;
    if (tid == 255) p.bsum[b] = tmp[255];
}

// scatter edges directly into final per-node segments
__device__ inline void dev_scat(int b, const Params& p) {
    const int base = b * EPB + threadIdx.x;
#pragma unroll
    for (int k = 0; k < EPB / 256; ++k) {
        int e = base + k * 256;
        if (e < p.E) {
            int s = p.ei[e];
            unsigned d = (unsigned)p.ei[p.E + e];
            float w = p.ew[e];
            int pos = p.lbase[d] + p.bpref[d >> 8] + (int)atomicAdd(&p.cur[d], 1u);
            p.erec[pos] = make_int2(s, __float_as_int(w));
        }
    }
}

// ---------------- MFMA GEMM body (R0-verified, unchanged) ----------------
template <bool IN_BF16>
__device__ inline void mfma_body(unsigned short* sE,
                                 const void* __restrict__ Xv,
                                 const unsigned short* __restrict__ Wt,
                                 unsigned short* __restrict__ H, int n, int blk) {
    const int tid = threadIdx.x;
    const int row0 = blk * 64;
    const int lane = tid & 63;
    const int wv = tid >> 6;
    const int qm = lane & 15;
    const int quad = lane >> 4;

    const int arow = row0 + wv * 16 + qm;
    const int ar = (arow < n) ? arow : (n - 1);

    f32x4 acc[8];
#pragma unroll
    for (int i = 0; i < 8; ++i) acc[i] = (f32x4){0.f, 0.f, 0.f, 0.f};

#pragma unroll
    for (int kb = 0; kb < 4; ++kb) {
        const int koff = kb * 32 + quad * 8;
        bf16x8 a;
        if (IN_BF16) {
            a = *(const bf16x8*)((const unsigned short*)Xv + (size_t)ar * 128 + koff);
        } else {
            const float* Xf = (const float*)Xv + (size_t)ar * 128 + koff;
            float4 v0 = *(const float4*)(Xf);
            float4 v1 = *(const float4*)(Xf + 4);
            union { bf16x8 v; ushort4 u[2]; } cv;
            cv.u[0].x = f2bf(v0.x); cv.u[0].y = f2bf(v0.y);
            cv.u[0].z = f2bf(v0.z); cv.u[0].w = f2bf(v0.w);
            cv.u[1].x = f2bf(v1.x); cv.u[1].y = f2bf(v1.y);
            cv.u[1].z = f2bf(v1.z); cv.u[1].w = f2bf(v1.w);
            a = cv.v;
        }
#pragma unroll
        for (int n0 = 0; n0 < 8; ++n0) {
            bf16x8 b = *(const bf16x8*)(Wt + (n0 * 16 + qm) * 128 + koff);
            acc[n0] = __builtin_amdgcn_mfma_f32_16x16x32_bf16(a, b, acc[n0], 0, 0, 0);
        }
    }

#pragma unroll
    for (int n0 = 0; n0 < 8; ++n0)
#pragma unroll
        for (int r = 0; r < 4; ++r)
            sE[(wv * 16 + quad * 4 + r) * 136 + n0 * 16 + qm] = f2bf(acc[n0][r]);
    __syncthreads();

    const int row_in = lane >> 2;
    const int c0 = (lane & 3) * 4;
    const int grow = row0 + wv * 16 + row_in;
    if (grow < n) {
#pragma unroll
        for (int j = 0; j < 4; ++j)
            *(int4*)(H + (size_t)grow * 128 + (c0 + j) * 8) =
                *(const int4*)(&sE[(wv * 16 + row_in) * 136 + (c0 + j) * 8]);
    }
}

// ---------------- gather body (R0-verified, 32 lanes/node; start computed inline) ----------------
template <bool OUT_BF16>
__device__ inline void gather_body(const Params& p, const ushort4* __restrict__ H4,
                                   const float4* __restrict__ bias4,
                                   void* __restrict__ OUTv, int g) {
    const int lane = threadIdx.x & 31;
    const int node = g * 8 + (threadIdx.x >> 5);
    if (node >= p.N) return;
    const int start = p.lbase[node] + p.bpref[node >> 8];
    const int m = p.cnt[node];
    const float di = p.dinv[node];

    float4 b = bias4[lane];
    ushort4 h = H4[(size_t)node * 32 + lane];
    float ax = di * bf2f(h.x);
    float ay = di * bf2f(h.y);
    float az = di * bf2f(h.z);
    float aw = di * bf2f(h.w);

    int j = 0;
    for (; j + 4 <= m; j += 4) {
        const int base = start + j;
        int2 e0 = p.erec[base + 0], e1 = p.erec[base + 1];
        int2 e2 = p.erec[base + 2], e3 = p.erec[base + 3];
        float w0 = p.dinv[e0.x] * __int_as_float(e0.y);
        float w1 = p.dinv[e1.x] * __int_as_float(e1.y);
        float w2 = p.dinv[e2.x] * __int_as_float(e2.y);
        float w3 = p.dinv[e3.x] * __int_as_float(e3.y);
        ushort4 v0 = H4[(size_t)e0.x * 32 + lane];
        ushort4 v1 = H4[(size_t)e1.x * 32 + lane];
        ushort4 v2 = H4[(size_t)e2.x * 32 + lane];
        ushort4 v3 = H4[(size_t)e3.x * 32 + lane];
        ax += w0 * bf2f(v0.x); ay += w0 * bf2f(v0.y); az += w0 * bf2f(v0.z); aw += w0 * bf2f(v0.w);
        ax += w1 * bf2f(v1.x); ay += w1 * bf2f(v1.y); az += w1 * bf2f(v1.z); aw += w1 * bf2f(v1.w);
        ax += w2 * bf2f(v2.x); ay += w2 * bf2f(v2.y); az += w2 * bf2f(v2.z); aw += w2 * bf2f(v2.w);
        ax += w3 * bf2f(v3.x); ay += w3 * bf2f(v3.y); az += w3 * bf2f(v3.z); aw += w3 * bf2f(v3.w);
    }
    for (; j < m; ++j) {
        int2 er = p.erec[start + j];
        float w = p.dinv[er.x] * __int_as_float(er.y);
        ushort4 v = H4[(size_t)er.x * 32 + lane];
        ax += w * bf2f(v.x); ay += w * bf2f(v.y); az += w * bf2f(v.z); aw += w * bf2f(v.w);
    }
    ax = b.x + di * ax; ay = b.y + di * ay;
    az = b.z + di * az; aw = b.w + di * aw;
    if (OUT_BF16) {
        ushort4 o;
        o.x = f2bf(fmaxf(ax, 0.f)); o.y = f2bf(fmaxf(ay, 0.f));
        o.z = f2bf(fmaxf(az, 0.f)); o.w = f2bf(fmaxf(aw, 0.f));
        ((ushort4*)OUTv)[(size_t)node * 32 + lane] = o;
    } else {
        float4 o; o.x = ax; o.y = ay; o.z = az; o.w = aw;
        ((float4*)OUTv)[(size_t)node * 32 + lane] = o;
    }
}

// ================= 7-kernel pipeline =================
__global__ __launch_bounds__(256, 4) void k_c0(Params p) {   // prep + hist
    if (blockIdx.x < 2) dev_prep(blockIdx.x, p);
    else dev_hist(blockIdx.x - 2, p);
}
__global__ __launch_bounds__(256, 4) void k_c1(Params p) {   // GEMM1 + node-scan
    __shared__ __align__(16) char arena[64 * 136 * 2];
    if ((int)blockIdx.x < p.gb)
        mfma_body<false>((unsigned short*)arena, (const void*)p.x, p.Wt1, p.Hbuf, p.N, blockIdx.x);
    else
        dev_scanL(blockIdx.x - p.gb, p, (int*)arena);
}
__global__ __launch_bounds__(256) void k_c2(Params p) {      // scan of block sums (1 block)
    __shared__ int tmp[256];
    __shared__ int carry;
    const int tid = threadIdx.x;
    if (tid == 0) carry = 0;
    __syncthreads();
    for (int base = 0; base < p.sn; base += 256) {
        int i = base + tid;
        int v = (i < p.sn) ? p.bsum[i] : 0;
        tmp[tid] = v;
        __syncthreads();
        for (int off = 1; off < 256; off <<= 1) {
            int t = (tid >= off) ? tmp[tid - off] : 0;
            __syncthreads();
            tmp[tid] += t;
            __syncthreads();
        }
        if (i < p.sn) p.bpref[i] = carry + tmp[tid] - v;
        __syncthreads();
        if (tid == 0) carry += tmp[255];
        __syncthreads();
    }
}
__global__ __launch_bounds__(256) void k_c3(Params p) {      // scatter -> erec (final order)
    dev_scat(blockIdx.x, p);
}
__global__ __launch_bounds__(256) void k_c4(Params p) {      // gather1 -> Abuf (bf16+ReLU)
    gather_body<true>(p, (const ushort4*)p.Hbuf, (const float4*)p.b1, (void*)p.Abuf, blockIdx.x);
}
__global__ __launch_bounds__(256, 4) void k_c5(Params p) {   // GEMM2
    __shared__ __align__(16) char arena[64 * 136 * 2];
    mfma_body<true>((unsigned short*)arena, (const void*)p.Abuf, p.Wt2, p.Hbuf, p.N, blockIdx.x);
}
__global__ __launch_bounds__(256) void k_c6(Params p) {      // gather2 -> out fp32
    gather_body<false>(p, (const ushort4*)p.Hbuf, (const float4*)p.b2, (void*)p.out, blockIdx.x);
}

extern "C" void kernel_launch(void* const* d_in, const int* in_sizes, int n_in,
                              void* d_out, int out_size, void* d_ws, size_t ws_size,
                              hipStream_t stream) {
    Params p;
    p.x  = (const float*)d_in[0];
    p.ei = (const int*)d_in[1];
    p.ew = (const float*)d_in[2];
    p.W1 = (const float*)d_in[3];
    p.b1 = (const float*)d_in[4];
    p.W2 = (const float*)d_in[5];
    p.b2 = (const float*)d_in[6];
    p.out = (float*)d_out;

    p.N = in_sizes[0] / D;
    p.E = in_sizes[2];
    p.hbn = (p.E + EPB - 1) / EPB;
    p.gb = (p.N + 63) / 64;
    p.hb = (p.N + 7) / 8;
    p.sn = (p.N + 255) / 256;

    char* w = (char*)d_ws;
    auto alloc = [&](size_t bytes) {
        void* r = (void*)w;
        w += (bytes + 255) & ~(size_t)255;
        return r;
    };
    // cntdeg and cur adjacent -> single memset covers both
    p.cntdeg   = (unsigned long long*)alloc((size_t)p.N * 8);
    p.cur      = (unsigned int*)alloc((size_t)p.N * 4);
    p.lbase    = (int*)alloc((size_t)p.N * 4);
    p.cnt      = (int*)alloc((size_t)p.N * 4);
    p.dinv     = (float*)alloc((size_t)p.N * 4);
    p.bsum     = (int*)alloc((size_t)(p.sn + 1) * 4);
    p.bpref    = (int*)alloc((size_t)(p.sn + 1) * 4);
    p.erec     = (int2*)alloc((size_t)p.E * 8);
    p.Hbuf     = (unsigned short*)alloc((size_t)p.N * D * 2);
    p.Abuf     = (unsigned short*)alloc((size_t)p.N * D * 2);
    p.Wt1      = (unsigned short*)alloc(128 * 128 * 2);
    p.Wt2      = (unsigned short*)alloc(128 * 128 * 2);

    size_t zspan = (size_t)((char*)p.cur - (char*)p.cntdeg) + (size_t)p.N * 4;
    hipMemsetAsync(p.cntdeg, 0, zspan, stream);

    k_c0<<<2 + p.hbn, 256, 0, stream>>>(p);
    k_c1<<<p.gb + p.sn, 256, 0, stream>>>(p);
    k_c2<<<1, 256, 0, stream>>>(p);
    k_c3<<<p.hbn, 256, 0, stream>>>(p);
    k_c4<<<p.hb, 256, 0, stream>>>(p);
    k_c5<<<p.gb, 256, 0, stream>>>(p);
    k_c6<<<p.hb, 256, 0, stream>>>(p);
}

// Round 5
// 224.233 us; speedup vs baseline: 1.1468x; 1.1468x over previous
//
#include <hip/hip_runtime.h>
#include <stdint.h>

#define D 128
#define EPB 4096   // edges per histogram/scatter block (R0-proven)
#define CSZ 128    // nodes per cluster (cluster = dst >> 7)

typedef __bf16 bf16x8 __attribute__((ext_vector_type(8)));
typedef float f32x4 __attribute__((ext_vector_type(4)));

__device__ inline float bf2f(unsigned short u) {
    return __uint_as_float((unsigned)u << 16);
}
__device__ inline unsigned short f2bf(float f) {
    unsigned u = __float_as_uint(f);
    return (unsigned short)((u + 0x7FFF + ((u >> 16) & 1)) >> 16);  // RNE
}

struct Params {
    const float* x; const int* ei; const float* ew;
    const float* W1; const float* b1; const float* W2; const float* b2;
    float* out;
    int N, E, C, B1n, total, gb, hb, sb;
    unsigned short *Wt1, *Wt2;
    unsigned int* bh; int* ebase; int* bsums;
    float* dinv; int* cnt; int* rowstart;
    int2* brec; int2* erec;
    unsigned short *Hbuf, *Abuf;
};

// ================= phase bodies (R0-verified, verbatim) =================

__device__ inline void dev_prep(int which, const Params& p) {
    const float* W = (which == 0) ? p.W1 : p.W2;
    unsigned short* Wt = (which == 0) ? p.Wt1 : p.Wt2;
    for (int i = threadIdx.x; i < 2048; i += 256) {
        int nn = i >> 4;
        int kc = (i & 15) << 3;
        ushort4 o0, o1;
        o0.x = f2bf(W[(kc + 0) * 128 + nn]); o0.y = f2bf(W[(kc + 1) * 128 + nn]);
        o0.z = f2bf(W[(kc + 2) * 128 + nn]); o0.w = f2bf(W[(kc + 3) * 128 + nn]);
        o1.x = f2bf(W[(kc + 4) * 128 + nn]); o1.y = f2bf(W[(kc + 5) * 128 + nn]);
        o1.z = f2bf(W[(kc + 6) * 128 + nn]); o1.w = f2bf(W[(kc + 7) * 128 + nn]);
        *(ushort4*)(Wt + nn * 128 + kc) = o0;
        *(ushort4*)(Wt + nn * 128 + kc + 4) = o1;
    }
}

__device__ inline void dev_hist(int b, const Params& p, unsigned int* hist) {
    for (int i = threadIdx.x; i < p.C; i += 256) hist[i] = 0;
    __syncthreads();
    const int base = b * EPB + threadIdx.x;
#pragma unroll
    for (int k = 0; k < EPB / 256; ++k) {
        int e = base + k * 256;
        if (e < p.E) atomicAdd(&hist[((unsigned)p.ei[p.E + e]) >> 7], 1u);
    }
    __syncthreads();
    for (int i = threadIdx.x; i < p.C; i += 256) p.bh[(size_t)b * p.C + i] = hist[i];
}

__device__ inline void dev_scanA(int blk, const Params& p, int* tmp) {
    const int tid = threadIdx.x;
    const int i = blk * 256 + tid;
    int v = 0;
    if (i < p.total) {
        int c = i / p.B1n;
        int b = i - c * p.B1n;
        v = (int)p.bh[(size_t)b * p.C + c];
    }
    tmp[tid] = v;
    __syncthreads();
    for (int off = 1; off < 256; off <<= 1) {
        int t = (tid >= off) ? tmp[tid - off] : 0;
        __syncthreads();
        tmp[tid] += t;
        __syncthreads();
    }
    if (i < p.total) p.ebase[i] = tmp[tid] - v;
    if (tid == 255) p.bsums[blk] = tmp[255];
}

__device__ inline void dev_scanB(int blk, const Params& p, int* sred) {
    const int tid = threadIdx.x;
    int v = (tid < blk) ? p.bsums[tid] : 0;
#pragma unroll
    for (int off = 32; off; off >>= 1) v += __shfl_down(v, off);
    if ((tid & 63) == 0) sred[tid >> 6] = v;
    __syncthreads();
    int tot = sred[0] + sred[1] + sred[2] + sred[3];
    int i = blk * 256 + tid;
    if (i < p.total) p.ebase[i] += tot;
}

__device__ inline void dev_scat(int b, const Params& p, unsigned int* cur) {
    for (int i = threadIdx.x; i < p.C; i += 256) cur[i] = 0;
    __syncthreads();
    const int base = b * EPB + threadIdx.x;
#pragma unroll
    for (int k = 0; k < EPB / 256; ++k) {
        int e = base + k * 256;
        if (e < p.E) {
            int s = p.ei[e];
            unsigned d = (unsigned)p.ei[p.E + e];
            float w = p.ew[e];
            int c = d >> 7;
            unsigned r = atomicAdd(&cur[c], 1u);
            int pos = p.ebase[c * p.B1n + b] + (int)r;
            p.brec[pos] = make_int2((int)((d << 16) | (unsigned)s), __float_as_int(w));
        }
    }
}

__device__ inline void dev_cbuild(int c, const Params& p, unsigned int* a) {
    unsigned int* hcnt = a;
    unsigned int* hdeg = a + CSZ;
    unsigned int* lsc  = a + 2 * CSZ;
    unsigned int* curs = a + 3 * CSZ;
    const int tid = threadIdx.x;
    const int cs = p.ebase[c * p.B1n];
    const int ce = (c + 1 < p.C) ? p.ebase[(c + 1) * p.B1n] : p.E;
    if (tid < CSZ) { hcnt[tid] = 0; hdeg[tid] = 0; }
    __syncthreads();
    for (int i = cs + tid; i < ce; i += 256) {
        int2 r = p.brec[i];
        int local = (int)(((unsigned)r.x) >> 16) & (CSZ - 1);
        atomicAdd(&hcnt[local], 1u);
        atomicAdd(&hdeg[local], (unsigned)(__int_as_float(r.y) * 16777216.0f));
    }
    __syncthreads();
    if (tid < CSZ) lsc[tid] = hcnt[tid];
    __syncthreads();
    for (int off = 1; off < CSZ; off <<= 1) {
        unsigned t = (tid < CSZ && tid >= off) ? lsc[tid - off] : 0u;
        __syncthreads();
        if (tid < CSZ) lsc[tid] += t;
        __syncthreads();
    }
    if (tid < CSZ) {
        unsigned excl = lsc[tid] - hcnt[tid];
        curs[tid] = excl;
        int node = c * CSZ + tid;
        if (node < p.N) {
            p.rowstart[node] = cs + (int)excl;
            p.cnt[node] = (int)hcnt[tid];
            float deg = 1.0f + (float)hdeg[tid] * (1.0f / 16777216.0f);
            p.dinv[node] = rsqrtf(deg);
        }
    }
    __syncthreads();
    for (int i = cs + tid; i < ce; i += 256) {
        int2 r = p.brec[i];
        int local = (int)(((unsigned)r.x) >> 16) & (CSZ - 1);
        unsigned rk = atomicAdd(&curs[local], 1u);
        p.erec[cs + (int)rk] = make_int2(r.x & 0xFFFF, r.y);   // (src, ew)
    }
}

// ---------------- MFMA GEMM body (R0-verified, verbatim): GEMM1 ----------------
template <bool IN_BF16>
__device__ inline void mfma_body(unsigned short* sE,
                                 const void* __restrict__ Xv,
                                 const unsigned short* __restrict__ Wt,
                                 unsigned short* __restrict__ H, int n, int blk) {
    const int tid = threadIdx.x;
    const int row0 = blk * 64;
    const int lane = tid & 63;
    const int wv = tid >> 6;
    const int qm = lane & 15;
    const int quad = lane >> 4;

    const int arow = row0 + wv * 16 + qm;
    const int ar = (arow < n) ? arow : (n - 1);

    f32x4 acc[8];
#pragma unroll
    for (int i = 0; i < 8; ++i) acc[i] = (f32x4){0.f, 0.f, 0.f, 0.f};

#pragma unroll
    for (int kb = 0; kb < 4; ++kb) {
        const int koff = kb * 32 + quad * 8;
        bf16x8 a;
        if (IN_BF16) {
            a = *(const bf16x8*)((const unsigned short*)Xv + (size_t)ar * 128 + koff);
        } else {
            const float* Xf = (const float*)Xv + (size_t)ar * 128 + koff;
            float4 v0 = *(const float4*)(Xf);
            float4 v1 = *(const float4*)(Xf + 4);
            union { bf16x8 v; ushort4 u[2]; } cv;
            cv.u[0].x = f2bf(v0.x); cv.u[0].y = f2bf(v0.y);
            cv.u[0].z = f2bf(v0.z); cv.u[0].w = f2bf(v0.w);
            cv.u[1].x = f2bf(v1.x); cv.u[1].y = f2bf(v1.y);
            cv.u[1].z = f2bf(v1.z); cv.u[1].w = f2bf(v1.w);
            a = cv.v;
        }
#pragma unroll
        for (int n0 = 0; n0 < 8; ++n0) {
            bf16x8 b = *(const bf16x8*)(Wt + (n0 * 16 + qm) * 128 + koff);
            acc[n0] = __builtin_amdgcn_mfma_f32_16x16x32_bf16(a, b, acc[n0], 0, 0, 0);
        }
    }

#pragma unroll
    for (int n0 = 0; n0 < 8; ++n0)
#pragma unroll
        for (int r = 0; r < 4; ++r)
            sE[(wv * 16 + quad * 4 + r) * 136 + n0 * 16 + qm] = f2bf(acc[n0][r]);
    __syncthreads();

    const int row_in = lane >> 2;
    const int c0 = (lane & 3) * 4;
    const int grow = row0 + wv * 16 + row_in;
    if (grow < n) {
#pragma unroll
        for (int j = 0; j < 4; ++j)
            *(int4*)(H + (size_t)grow * 128 + (c0 + j) * 8) =
                *(const int4*)(&sE[(wv * 16 + row_in) * 136 + (c0 + j) * 8]);
    }
}

// ---------------- gather layer-1 into LDS (R2-verified, verbatim) ----------------
__device__ inline void gather1_to_lds(const Params& p, unsigned short* sA, int row0) {
    const int tid = threadIdx.x;
    const int lane8 = tid & 7;
    const int grp = tid >> 3;  // 0..31
    const ushort4* __restrict__ H4 = (const ushort4*)p.Hbuf;
#pragma unroll
    for (int pass = 0; pass < 2; ++pass) {
        const int local = pass * 32 + grp;
        const int node = row0 + local;
        unsigned short* dst = sA + local * 136 + lane8 * 16;
        if (node < p.N) {
            const int start = p.rowstart[node];
            const int m = p.cnt[node];
            const float di = p.dinv[node];
            const ushort4* Hrow = H4 + (size_t)node * 32 + lane8 * 4;
            float acc[16];
#pragma unroll
            for (int q = 0; q < 4; ++q) {
                ushort4 h = Hrow[q];
                acc[q * 4 + 0] = di * bf2f(h.x);
                acc[q * 4 + 1] = di * bf2f(h.y);
                acc[q * 4 + 2] = di * bf2f(h.z);
                acc[q * 4 + 3] = di * bf2f(h.w);
            }
            int j = 0;
            for (; j + 2 <= m; j += 2) {
                int2 e0 = p.erec[start + j];
                int2 e1 = p.erec[start + j + 1];
                float w0 = p.dinv[e0.x] * __int_as_float(e0.y);
                float w1 = p.dinv[e1.x] * __int_as_float(e1.y);
                const ushort4* V0 = H4 + (size_t)e0.x * 32 + lane8 * 4;
                const ushort4* V1 = H4 + (size_t)e1.x * 32 + lane8 * 4;
#pragma unroll
                for (int q = 0; q < 4; ++q) {
                    ushort4 v0 = V0[q], v1 = V1[q];
                    acc[q * 4 + 0] += w0 * bf2f(v0.x) + w1 * bf2f(v1.x);
                    acc[q * 4 + 1] += w0 * bf2f(v0.y) + w1 * bf2f(v1.y);
                    acc[q * 4 + 2] += w0 * bf2f(v0.z) + w1 * bf2f(v1.z);
                    acc[q * 4 + 3] += w0 * bf2f(v0.w) + w1 * bf2f(v1.w);
                }
            }
            if (j < m) {
                int2 e0 = p.erec[start + j];
                float w0 = p.dinv[e0.x] * __int_as_float(e0.y);
                const ushort4* V0 = H4 + (size_t)e0.x * 32 + lane8 * 4;
#pragma unroll
                for (int q = 0; q < 4; ++q) {
                    ushort4 v0 = V0[q];
                    acc[q * 4 + 0] += w0 * bf2f(v0.x);
                    acc[q * 4 + 1] += w0 * bf2f(v0.y);
                    acc[q * 4 + 2] += w0 * bf2f(v0.z);
                    acc[q * 4 + 3] += w0 * bf2f(v0.w);
                }
            }
            const float* bb = p.b1 + lane8 * 16;
#pragma unroll
            for (int q = 0; q < 4; ++q) {
                ushort4 o;
                o.x = f2bf(fmaxf(bb[q * 4 + 0] + di * acc[q * 4 + 0], 0.f));
                o.y = f2bf(fmaxf(bb[q * 4 + 1] + di * acc[q * 4 + 1], 0.f));
                o.z = f2bf(fmaxf(bb[q * 4 + 2] + di * acc[q * 4 + 2], 0.f));
                o.w = f2bf(fmaxf(bb[q * 4 + 3] + di * acc[q * 4 + 3], 0.f));
                *(ushort4*)(dst + q * 4) = o;
            }
        } else {
            ushort4 z = {0, 0, 0, 0};
#pragma unroll
            for (int q = 0; q < 4; ++q) *(ushort4*)(dst + q * 4) = z;
        }
    }
}

// ---------------- gather layer 2: out = b2 + dinv[d]*(H2s[d] + sum ew*H2s[src]) ----------------
// H2s rows are pre-scaled by dinv (folded into the fused GEMM2 epilogue, fp32) -> no per-edge dinv load.
__device__ inline void gather2_body(const Params& p, const ushort4* __restrict__ H4,
                                    const float4* __restrict__ bias4,
                                    float4* __restrict__ OUT, int g) {
    const int lane = threadIdx.x & 31;
    const int node = g * 8 + (threadIdx.x >> 5);
    if (node >= p.N) return;
    const int start = p.rowstart[node];
    const int m = p.cnt[node];
    const float di = p.dinv[node];

    float4 b = bias4[lane];
    ushort4 h = H4[(size_t)node * 32 + lane];
    float ax = bf2f(h.x);
    float ay = bf2f(h.y);
    float az = bf2f(h.z);
    float aw = bf2f(h.w);

    int j = 0;
    for (; j + 4 <= m; j += 4) {
        const int base = start + j;
        int2 e0 = p.erec[base + 0], e1 = p.erec[base + 1];
        int2 e2 = p.erec[base + 2], e3 = p.erec[base + 3];
        float w0 = __int_as_float(e0.y);
        float w1 = __int_as_float(e1.y);
        float w2 = __int_as_float(e2.y);
        float w3 = __int_as_float(e3.y);
        ushort4 v0 = H4[(size_t)e0.x * 32 + lane];
        ushort4 v1 = H4[(size_t)e1.x * 32 + lane];
        ushort4 v2 = H4[(size_t)e2.x * 32 + lane];
        ushort4 v3 = H4[(size_t)e3.x * 32 + lane];
        ax += w0 * bf2f(v0.x); ay += w0 * bf2f(v0.y); az += w0 * bf2f(v0.z); aw += w0 * bf2f(v0.w);
        ax += w1 * bf2f(v1.x); ay += w1 * bf2f(v1.y); az += w1 * bf2f(v1.z); aw += w1 * bf2f(v1.w);
        ax += w2 * bf2f(v2.x); ay += w2 * bf2f(v2.y); az += w2 * bf2f(v2.z); aw += w2 * bf2f(v2.w);
        ax += w3 * bf2f(v3.x); ay += w3 * bf2f(v3.y); az += w3 * bf2f(v3.z); aw += w3 * bf2f(v3.w);
    }
    for (; j < m; ++j) {
        int2 er = p.erec[start + j];
        float w = __int_as_float(er.y);
        ushort4 v = H4[(size_t)er.x * 32 + lane];
        ax += w * bf2f(v.x); ay += w * bf2f(v.y); az += w * bf2f(v.z); aw += w * bf2f(v.w);
    }
    float4 o;
    o.x = b.x + di * ax; o.y = b.y + di * ay;
    o.z = b.z + di * az; o.w = b.w + di * aw;
    OUT[(size_t)node * 32 + lane] = o;
}

// ================= 7-kernel pipeline =================
__global__ __launch_bounds__(256, 4) void k_f0(Params p) {   // prep + hist
    __shared__ __align__(16) unsigned int hist[512];
    if (blockIdx.x < 2) dev_prep(blockIdx.x, p);
    else dev_hist(blockIdx.x - 2, p, hist);
}
__global__ __launch_bounds__(256, 4) void k_f1(Params p) {   // GEMM1 + scanA
    __shared__ __align__(16) char arena[64 * 136 * 2];
    if ((int)blockIdx.x < p.gb) mfma_body<false>((unsigned short*)arena, (const void*)p.x, p.Wt1, p.Hbuf, p.N, blockIdx.x);
    else dev_scanA(blockIdx.x - p.gb, p, (int*)arena);
}
__global__ __launch_bounds__(256) void k_f2(Params p) {      // scanB
    __shared__ int sred[4];
    dev_scanB(blockIdx.x, p, sred);
}
__global__ __launch_bounds__(256) void k_f3(Params p) {      // scatter -> brec
    __shared__ unsigned int cur[512];
    dev_scat(blockIdx.x, p, cur);
}
__global__ __launch_bounds__(256) void k_f4(Params p) {      // CSR build -> erec/dinv/cnt/rowstart
    __shared__ unsigned int a[4 * CSZ];
    dev_cbuild(blockIdx.x, p, a);
}
// fused gather1 + GEMM2 (single shared arena; 8 blocks/CU); epilogue folds dinv -> H2s (Abuf)
__global__ __launch_bounds__(256, 8) void k_g5(Params p) {
    __shared__ __align__(16) unsigned short sA[64 * 136];    // 17408 B, reused for epilogue staging
    const int row0 = blockIdx.x * 64;
    gather1_to_lds(p, sA, row0);
    __syncthreads();

    const int tid = threadIdx.x;
    const int lane = tid & 63;
    const int wv = tid >> 6;
    const int qm = lane & 15;
    const int quad = lane >> 4;

    f32x4 acc[8];
#pragma unroll
    for (int i = 0; i < 8; ++i) acc[i] = (f32x4){0.f, 0.f, 0.f, 0.f};

#pragma unroll
    for (int kb = 0; kb < 4; ++kb) {
        const int koff = kb * 32 + quad * 8;
        bf16x8 a = *(const bf16x8*)(sA + (wv * 16 + qm) * 136 + koff);
#pragma unroll
        for (int n0 = 0; n0 < 8; ++n0) {
            bf16x8 b = *(const bf16x8*)(p.Wt2 + (n0 * 16 + qm) * 128 + koff);
            acc[n0] = __builtin_amdgcn_mfma_f32_16x16x32_bf16(a, b, acc[n0], 0, 0, 0);
        }
    }

    // per-C-row dinv (fold into H2s, fp32 before the single bf16 rounding)
    const int crow = wv * 16 + quad * 4;
    float di[4];
#pragma unroll
    for (int r = 0; r < 4; ++r) {
        int rr = row0 + crow + r;
        int rc = (rr < p.N) ? rr : (p.N - 1);
        di[r] = p.dinv[rc];
    }

    __syncthreads();   // all A-fragment reads complete before arena reuse
#pragma unroll
    for (int n0 = 0; n0 < 8; ++n0)
#pragma unroll
        for (int r = 0; r < 4; ++r)
            sA[(crow + r) * 136 + n0 * 16 + qm] = f2bf(acc[n0][r] * di[r]);
    __syncthreads();

    const int row_in = lane >> 2;
    const int c0 = (lane & 3) * 4;
    const int grow = row0 + wv * 16 + row_in;
    if (grow < p.N) {
#pragma unroll
        for (int j = 0; j < 4; ++j)
            *(int4*)(p.Abuf + (size_t)grow * 128 + (c0 + j) * 8) =
                *(const int4*)(&sA[(wv * 16 + row_in) * 136 + (c0 + j) * 8]);
    }
}
__global__ __launch_bounds__(256) void k_g6(Params p) {      // gather2 -> out fp32
    gather2_body(p, (const ushort4*)p.Abuf, (const float4*)p.b2, (float4*)p.out, blockIdx.x);
}

extern "C" void kernel_launch(void* const* d_in, const int* in_sizes, int n_in,
                              void* d_out, int out_size, void* d_ws, size_t ws_size,
                              hipStream_t stream) {
    Params p;
    p.x  = (const float*)d_in[0];
    p.ei = (const int*)d_in[1];
    p.ew = (const float*)d_in[2];
    p.W1 = (const float*)d_in[3];
    p.b1 = (const float*)d_in[4];
    p.W2 = (const float*)d_in[5];
    p.b2 = (const float*)d_in[6];
    p.out = (float*)d_out;

    p.N = in_sizes[0] / D;
    p.E = in_sizes[2];
    p.C = (p.N + CSZ - 1) / CSZ;
    p.B1n = (p.E + EPB - 1) / EPB;
    p.total = p.C * p.B1n;
    p.sb = (p.total + 255) / 256;
    p.gb = (p.N + 63) / 64;
    p.hb = (p.N + 7) / 8;

    char* w = (char*)d_ws;
    auto alloc = [&](size_t bytes) {
        void* r = (void*)w;
        w += (bytes + 255) & ~(size_t)255;
        return r;
    };
    p.bh       = (unsigned int*)alloc((size_t)p.total * 4);
    p.ebase    = (int*)alloc((size_t)p.total * 4);
    p.bsums    = (int*)alloc(1024 * 4);
    p.dinv     = (float*)alloc((size_t)p.N * 4);
    p.cnt      = (int*)alloc((size_t)p.N * 4);
    p.rowstart = (int*)alloc((size_t)p.N * 4);
    p.brec     = (int2*)alloc((size_t)p.E * 8);
    p.erec     = (int2*)alloc((size_t)p.E * 8);
    p.Hbuf     = (unsigned short*)alloc((size_t)p.N * D * 2);
    p.Abuf     = (unsigned short*)alloc((size_t)p.N * D * 2);
    p.Wt1      = (unsigned short*)alloc(128 * 128 * 2);
    p.Wt2      = (unsigned short*)alloc(128 * 128 * 2);

    k_f0<<<2 + p.B1n, 256, 0, stream>>>(p);
    k_f1<<<p.gb + p.sb, 256, 0, stream>>>(p);
    k_f2<<<p.sb, 256, 0, stream>>>(p);
    k_f3<<<p.B1n, 256, 0, stream>>>(p);
    k_f4<<<p.C, 256, 0, stream>>>(p);
    k_g5<<<p.gb, 256, 0, stream>>>(p);
    k_g6<<<p.hb, 256, 0, stream>>>(p);
}

// Round 6
// 204.259 us; speedup vs baseline: 1.2590x; 1.0978x over previous
//
#include <hip/hip_runtime.h>
#include <stdint.h>

#define D 128
#define EPB 4096   // edges per histogram/scatter block (R0-proven)
#define CSZ 128    // nodes per cluster (cluster = dst >> 7)

typedef __bf16 bf16x8 __attribute__((ext_vector_type(8)));
typedef float f32x4 __attribute__((ext_vector_type(4)));

__device__ inline float bf2f(unsigned short u) {
    return __uint_as_float((unsigned)u << 16);
}
__device__ inline unsigned short f2bf(float f) {
    unsigned u = __float_as_uint(f);
    return (unsigned short)((u + 0x7FFF + ((u >> 16) & 1)) >> 16);  // RNE
}

struct Params {
    const float* x; const int* ei; const float* ew;
    const float* W1; const float* b1; const float* W2; const float* b2;
    float* out;
    int N, E, C, B1n, total, gb, hb, sb;
    unsigned short *Wt1, *Wt2;
    unsigned int* bh; int* ebase; int* bsums;
    float* dinv; int* cnt; int* rowstart;
    int2* brec; int2* erec;
    unsigned short *Hbuf, *Abuf;
};

// ================= phase bodies (R0-verified, verbatim) =================

__device__ inline void dev_prep(int which, const Params& p) {
    const float* W = (which == 0) ? p.W1 : p.W2;
    unsigned short* Wt = (which == 0) ? p.Wt1 : p.Wt2;
    for (int i = threadIdx.x; i < 2048; i += 256) {
        int nn = i >> 4;
        int kc = (i & 15) << 3;
        ushort4 o0, o1;
        o0.x = f2bf(W[(kc + 0) * 128 + nn]); o0.y = f2bf(W[(kc + 1) * 128 + nn]);
        o0.z = f2bf(W[(kc + 2) * 128 + nn]); o0.w = f2bf(W[(kc + 3) * 128 + nn]);
        o1.x = f2bf(W[(kc + 4) * 128 + nn]); o1.y = f2bf(W[(kc + 5) * 128 + nn]);
        o1.z = f2bf(W[(kc + 6) * 128 + nn]); o1.w = f2bf(W[(kc + 7) * 128 + nn]);
        *(ushort4*)(Wt + nn * 128 + kc) = o0;
        *(ushort4*)(Wt + nn * 128 + kc + 4) = o1;
    }
}

__device__ inline void dev_hist(int b, const Params& p, unsigned int* hist) {
    for (int i = threadIdx.x; i < p.C; i += 256) hist[i] = 0;
    __syncthreads();
    const int base = b * EPB + threadIdx.x;
#pragma unroll
    for (int k = 0; k < EPB / 256; ++k) {
        int e = base + k * 256;
        if (e < p.E) atomicAdd(&hist[((unsigned)p.ei[p.E + e]) >> 7], 1u);
    }
    __syncthreads();
    for (int i = threadIdx.x; i < p.C; i += 256) p.bh[(size_t)b * p.C + i] = hist[i];
}

__device__ inline void dev_scanA(int blk, const Params& p, int* tmp) {
    const int tid = threadIdx.x;
    const int i = blk * 256 + tid;
    int v = 0;
    if (i < p.total) {
        int c = i / p.B1n;
        int b = i - c * p.B1n;
        v = (int)p.bh[(size_t)b * p.C + c];
    }
    tmp[tid] = v;
    __syncthreads();
    for (int off = 1; off < 256; off <<= 1) {
        int t = (tid >= off) ? tmp[tid - off] : 0;
        __syncthreads();
        tmp[tid] += t;
        __syncthreads();
    }
    if (i < p.total) p.ebase[i] = tmp[tid] - v;
    if (tid == 255) p.bsums[blk] = tmp[255];
}

__device__ inline void dev_scanB(int blk, const Params& p, int* sred) {
    const int tid = threadIdx.x;
    int v = (tid < blk) ? p.bsums[tid] : 0;
#pragma unroll
    for (int off = 32; off; off >>= 1) v += __shfl_down(v, off);
    if ((tid & 63) == 0) sred[tid >> 6] = v;
    __syncthreads();
    int tot = sred[0] + sred[1] + sred[2] + sred[3];
    int i = blk * 256 + tid;
    if (i < p.total) p.ebase[i] += tot;
}

__device__ inline void dev_scat(int b, const Params& p, unsigned int* cur) {
    for (int i = threadIdx.x; i < p.C; i += 256) cur[i] = 0;
    __syncthreads();
    const int base = b * EPB + threadIdx.x;
#pragma unroll
    for (int k = 0; k < EPB / 256; ++k) {
        int e = base + k * 256;
        if (e < p.E) {
            int s = p.ei[e];
            unsigned d = (unsigned)p.ei[p.E + e];
            float w = p.ew[e];
            int c = d >> 7;
            unsigned r = atomicAdd(&cur[c], 1u);
            int pos = p.ebase[c * p.B1n + b] + (int)r;
            p.brec[pos] = make_int2((int)((d << 16) | (unsigned)s), __float_as_int(w));
        }
    }
}

__device__ inline void dev_cbuild(int c, const Params& p, unsigned int* a) {
    unsigned int* hcnt = a;
    unsigned int* hdeg = a + CSZ;
    unsigned int* lsc  = a + 2 * CSZ;
    unsigned int* curs = a + 3 * CSZ;
    const int tid = threadIdx.x;
    const int cs = p.ebase[c * p.B1n];
    const int ce = (c + 1 < p.C) ? p.ebase[(c + 1) * p.B1n] : p.E;
    if (tid < CSZ) { hcnt[tid] = 0; hdeg[tid] = 0; }
    __syncthreads();
    for (int i = cs + tid; i < ce; i += 256) {
        int2 r = p.brec[i];
        int local = (int)(((unsigned)r.x) >> 16) & (CSZ - 1);
        atomicAdd(&hcnt[local], 1u);
        atomicAdd(&hdeg[local], (unsigned)(__int_as_float(r.y) * 16777216.0f));
    }
    __syncthreads();
    if (tid < CSZ) lsc[tid] = hcnt[tid];
    __syncthreads();
    for (int off = 1; off < CSZ; off <<= 1) {
        unsigned t = (tid < CSZ && tid >= off) ? lsc[tid - off] : 0u;
        __syncthreads();
        if (tid < CSZ) lsc[tid] += t;
        __syncthreads();
    }
    if (tid < CSZ) {
        unsigned excl = lsc[tid] - hcnt[tid];
        curs[tid] = excl;
        int node = c * CSZ + tid;
        if (node < p.N) {
            p.rowstart[node] = cs + (int)excl;
            p.cnt[node] = (int)hcnt[tid];
            float deg = 1.0f + (float)hdeg[tid] * (1.0f / 16777216.0f);
            p.dinv[node] = rsqrtf(deg);
        }
    }
    __syncthreads();
    for (int i = cs + tid; i < ce; i += 256) {
        int2 r = p.brec[i];
        int local = (int)(((unsigned)r.x) >> 16) & (CSZ - 1);
        unsigned rk = atomicAdd(&curs[local], 1u);
        p.erec[cs + (int)rk] = make_int2(r.x & 0xFFFF, r.y);   // (src, ew)
    }
}

// ---------------- MFMA GEMM body (R0-verified, verbatim): GEMM1 ----------------
template <bool IN_BF16>
__device__ inline void mfma_body(unsigned short* sE,
                                 const void* __restrict__ Xv,
                                 const unsigned short* __restrict__ Wt,
                                 unsigned short* __restrict__ H, int n, int blk) {
    const int tid = threadIdx.x;
    const int row0 = blk * 64;
    const int lane = tid & 63;
    const int wv = tid >> 6;
    const int qm = lane & 15;
    const int quad = lane >> 4;

    const int arow = row0 + wv * 16 + qm;
    const int ar = (arow < n) ? arow : (n - 1);

    f32x4 acc[8];
#pragma unroll
    for (int i = 0; i < 8; ++i) acc[i] = (f32x4){0.f, 0.f, 0.f, 0.f};

#pragma unroll
    for (int kb = 0; kb < 4; ++kb) {
        const int koff = kb * 32 + quad * 8;
        bf16x8 a;
        if (IN_BF16) {
            a = *(const bf16x8*)((const unsigned short*)Xv + (size_t)ar * 128 + koff);
        } else {
            const float* Xf = (const float*)Xv + (size_t)ar * 128 + koff;
            float4 v0 = *(const float4*)(Xf);
            float4 v1 = *(const float4*)(Xf + 4);
            union { bf16x8 v; ushort4 u[2]; } cv;
            cv.u[0].x = f2bf(v0.x); cv.u[0].y = f2bf(v0.y);
            cv.u[0].z = f2bf(v0.z); cv.u[0].w = f2bf(v0.w);
            cv.u[1].x = f2bf(v1.x); cv.u[1].y = f2bf(v1.y);
            cv.u[1].z = f2bf(v1.z); cv.u[1].w = f2bf(v1.w);
            a = cv.v;
        }
#pragma unroll
        for (int n0 = 0; n0 < 8; ++n0) {
            bf16x8 b = *(const bf16x8*)(Wt + (n0 * 16 + qm) * 128 + koff);
            acc[n0] = __builtin_amdgcn_mfma_f32_16x16x32_bf16(a, b, acc[n0], 0, 0, 0);
        }
    }

#pragma unroll
    for (int n0 = 0; n0 < 8; ++n0)
#pragma unroll
        for (int r = 0; r < 4; ++r)
            sE[(wv * 16 + quad * 4 + r) * 136 + n0 * 16 + qm] = f2bf(acc[n0][r]);
    __syncthreads();

    const int row_in = lane >> 2;
    const int c0 = (lane & 3) * 4;
    const int grow = row0 + wv * 16 + row_in;
    if (grow < n) {
#pragma unroll
        for (int j = 0; j < 4; ++j)
            *(int4*)(H + (size_t)grow * 128 + (c0 + j) * 8) =
                *(const int4*)(&sE[(wv * 16 + row_in) * 136 + (c0 + j) * 8]);
    }
}

// ---------------- gather layer-1 into LDS (R2-verified, verbatim) ----------------
__device__ inline void gather1_to_lds(const Params& p, unsigned short* sA, int row0) {
    const int tid = threadIdx.x;
    const int lane8 = tid & 7;
    const int grp = tid >> 3;  // 0..31
    const ushort4* __restrict__ H4 = (const ushort4*)p.Hbuf;
#pragma unroll
    for (int pass = 0; pass < 2; ++pass) {
        const int local = pass * 32 + grp;
        const int node = row0 + local;
        unsigned short* dst = sA + local * 136 + lane8 * 16;
        if (node < p.N) {
            const int start = p.rowstart[node];
            const int m = p.cnt[node];
            const float di = p.dinv[node];
            const ushort4* Hrow = H4 + (size_t)node * 32 + lane8 * 4;
            float acc[16];
#pragma unroll
            for (int q = 0; q < 4; ++q) {
                ushort4 h = Hrow[q];
                acc[q * 4 + 0] = di * bf2f(h.x);
                acc[q * 4 + 1] = di * bf2f(h.y);
                acc[q * 4 + 2] = di * bf2f(h.z);
                acc[q * 4 + 3] = di * bf2f(h.w);
            }
            int j = 0;
            for (; j + 2 <= m; j += 2) {
                int2 e0 = p.erec[start + j];
                int2 e1 = p.erec[start + j + 1];
                float w0 = p.dinv[e0.x] * __int_as_float(e0.y);
                float w1 = p.dinv[e1.x] * __int_as_float(e1.y);
                const ushort4* V0 = H4 + (size_t)e0.x * 32 + lane8 * 4;
                const ushort4* V1 = H4 + (size_t)e1.x * 32 + lane8 * 4;
#pragma unroll
                for (int q = 0; q < 4; ++q) {
                    ushort4 v0 = V0[q], v1 = V1[q];
                    acc[q * 4 + 0] += w0 * bf2f(v0.x) + w1 * bf2f(v1.x);
                    acc[q * 4 + 1] += w0 * bf2f(v0.y) + w1 * bf2f(v1.y);
                    acc[q * 4 + 2] += w0 * bf2f(v0.z) + w1 * bf2f(v1.z);
                    acc[q * 4 + 3] += w0 * bf2f(v0.w) + w1 * bf2f(v1.w);
                }
            }
            if (j < m) {
                int2 e0 = p.erec[start + j];
                float w0 = p.dinv[e0.x] * __int_as_float(e0.y);
                const ushort4* V0 = H4 + (size_t)e0.x * 32 + lane8 * 4;
#pragma unroll
                for (int q = 0; q < 4; ++q) {
                    ushort4 v0 = V0[q];
                    acc[q * 4 + 0] += w0 * bf2f(v0.x);
                    acc[q * 4 + 1] += w0 * bf2f(v0.y);
                    acc[q * 4 + 2] += w0 * bf2f(v0.z);
                    acc[q * 4 + 3] += w0 * bf2f(v0.w);
                }
            }
            const float* bb = p.b1 + lane8 * 16;
#pragma unroll
            for (int q = 0; q < 4; ++q) {
                ushort4 o;
                o.x = f2bf(fmaxf(bb[q * 4 + 0] + di * acc[q * 4 + 0], 0.f));
                o.y = f2bf(fmaxf(bb[q * 4 + 1] + di * acc[q * 4 + 1], 0.f));
                o.z = f2bf(fmaxf(bb[q * 4 + 2] + di * acc[q * 4 + 2], 0.f));
                o.w = f2bf(fmaxf(bb[q * 4 + 3] + di * acc[q * 4 + 3], 0.f));
                *(ushort4*)(dst + q * 4) = o;
            }
        } else {
            ushort4 z = {0, 0, 0, 0};
#pragma unroll
            for (int q = 0; q < 4; ++q) *(ushort4*)(dst + q * 4) = z;
        }
    }
}

// ---------------- gather layer 2: out = b2 + dinv[d]*(H2s[d] + sum ew*H2s[src]) ----------------
// H2s rows pre-scaled by dinv (folded into fused GEMM2 epilogue, fp32) -> no per-edge dinv load.
__device__ inline void gather2_body(const Params& p, const ushort4* __restrict__ H4,
                                    const float4* __restrict__ bias4,
                                    float4* __restrict__ OUT, int g) {
    const int lane = threadIdx.x & 31;
    const int node = g * 8 + (threadIdx.x >> 5);
    if (node >= p.N) return;
    const int start = p.rowstart[node];
    const int m = p.cnt[node];
    const float di = p.dinv[node];

    float4 b = bias4[lane];
    ushort4 h = H4[(size_t)node * 32 + lane];
    float ax = bf2f(h.x);
    float ay = bf2f(h.y);
    float az = bf2f(h.z);
    float aw = bf2f(h.w);

    int j = 0;
    for (; j + 4 <= m; j += 4) {
        const int base = start + j;
        int2 e0 = p.erec[base + 0], e1 = p.erec[base + 1];
        int2 e2 = p.erec[base + 2], e3 = p.erec[base + 3];
        float w0 = __int_as_float(e0.y);
        float w1 = __int_as_float(e1.y);
        float w2 = __int_as_float(e2.y);
        float w3 = __int_as_float(e3.y);
        ushort4 v0 = H4[(size_t)e0.x * 32 + lane];
        ushort4 v1 = H4[(size_t)e1.x * 32 + lane];
        ushort4 v2 = H4[(size_t)e2.x * 32 + lane];
        ushort4 v3 = H4[(size_t)e3.x * 32 + lane];
        ax += w0 * bf2f(v0.x); ay += w0 * bf2f(v0.y); az += w0 * bf2f(v0.z); aw += w0 * bf2f(v0.w);
        ax += w1 * bf2f(v1.x); ay += w1 * bf2f(v1.y); az += w1 * bf2f(v1.z); aw += w1 * bf2f(v1.w);
        ax += w2 * bf2f(v2.x); ay += w2 * bf2f(v2.y); az += w2 * bf2f(v2.z); aw += w2 * bf2f(v2.w);
        ax += w3 * bf2f(v3.x); ay += w3 * bf2f(v3.y); az += w3 * bf2f(v3.z); aw += w3 * bf2f(v3.w);
    }
    for (; j < m; ++j) {
        int2 er = p.erec[start + j];
        float w = __int_as_float(er.y);
        ushort4 v = H4[(size_t)er.x * 32 + lane];
        ax += w * bf2f(v.x); ay += w * bf2f(v.y); az += w * bf2f(v.z); aw += w * bf2f(v.w);
    }
    float4 o;
    o.x = b.x + di * ax; o.y = b.y + di * ay;
    o.z = b.z + di * az; o.w = b.w + di * aw;
    OUT[(size_t)node * 32 + lane] = o;
}

// ================= 7-kernel pipeline =================
__global__ __launch_bounds__(256, 4) void k_f0(Params p) {   // prep + hist
    __shared__ __align__(16) unsigned int hist[512];
    if (blockIdx.x < 2) dev_prep(blockIdx.x, p);
    else dev_hist(blockIdx.x - 2, p, hist);
}
__global__ __launch_bounds__(256, 4) void k_f1(Params p) {   // GEMM1 + scanA
    __shared__ __align__(16) char arena[64 * 136 * 2];
    if ((int)blockIdx.x < p.gb) mfma_body<false>((unsigned short*)arena, (const void*)p.x, p.Wt1, p.Hbuf, p.N, blockIdx.x);
    else dev_scanA(blockIdx.x - p.gb, p, (int*)arena);
}
__global__ __launch_bounds__(256) void k_f2(Params p) {      // scanB
    __shared__ int sred[4];
    dev_scanB(blockIdx.x, p, sred);
}
__global__ __launch_bounds__(256) void k_f3(Params p) {      // scatter -> brec
    __shared__ unsigned int cur[512];
    dev_scat(blockIdx.x, p, cur);
}
__global__ __launch_bounds__(256) void k_f4(Params p) {      // CSR build -> erec/dinv/cnt/rowstart
    __shared__ unsigned int a[4 * CSZ];
    dev_cbuild(blockIdx.x, p, a);
}
// fused gather1 + GEMM2 (R2-exact shape: two arenas, bounds(256,4), VGPR free) + dinv-fold epilogue
__global__ __launch_bounds__(256, 4) void k_g5(Params p) {
    __shared__ __align__(16) unsigned short sA[64 * 136];
    __shared__ __align__(16) unsigned short sE[64 * 136];
    const int row0 = blockIdx.x * 64;
    gather1_to_lds(p, sA, row0);
    __syncthreads();

    const int tid = threadIdx.x;
    const int lane = tid & 63;
    const int wv = tid >> 6;
    const int qm = lane & 15;
    const int quad = lane >> 4;

    f32x4 acc[8];
#pragma unroll
    for (int i = 0; i < 8; ++i) acc[i] = (f32x4){0.f, 0.f, 0.f, 0.f};

#pragma unroll
    for (int kb = 0; kb < 4; ++kb) {
        const int koff = kb * 32 + quad * 8;
        bf16x8 a = *(const bf16x8*)(sA + (wv * 16 + qm) * 136 + koff);
#pragma unroll
        for (int n0 = 0; n0 < 8; ++n0) {
            bf16x8 b = *(const bf16x8*)(p.Wt2 + (n0 * 16 + qm) * 128 + koff);
            acc[n0] = __builtin_amdgcn_mfma_f32_16x16x32_bf16(a, b, acc[n0], 0, 0, 0);
        }
    }

    // per-C-row dinv (fold into H2s, fp32 before the single bf16 rounding)
    const int crow = wv * 16 + quad * 4;
    float di[4];
#pragma unroll
    for (int r = 0; r < 4; ++r) {
        int rr = row0 + crow + r;
        int rc = (rr < p.N) ? rr : (p.N - 1);
        di[r] = p.dinv[rc];
    }

#pragma unroll
    for (int n0 = 0; n0 < 8; ++n0)
#pragma unroll
        for (int r = 0; r < 4; ++r)
            sE[(crow + r) * 136 + n0 * 16 + qm] = f2bf(acc[n0][r] * di[r]);
    __syncthreads();

    const int row_in = lane >> 2;
    const int c0 = (lane & 3) * 4;
    const int grow = row0 + wv * 16 + row_in;
    if (grow < p.N) {
#pragma unroll
        for (int j = 0; j < 4; ++j)
            *(int4*)(p.Abuf + (size_t)grow * 128 + (c0 + j) * 8) =
                *(const int4*)(&sE[(wv * 16 + row_in) * 136 + (c0 + j) * 8]);
    }
}
__global__ __launch_bounds__(256) void k_g6(Params p) {      // gather2 -> out fp32
    gather2_body(p, (const ushort4*)p.Abuf, (const float4*)p.b2, (float4*)p.out, blockIdx.x);
}

extern "C" void kernel_launch(void* const* d_in, const int* in_sizes, int n_in,
                              void* d_out, int out_size, void* d_ws, size_t ws_size,
                              hipStream_t stream) {
    Params p;
    p.x  = (const float*)d_in[0];
    p.ei = (const int*)d_in[1];
    p.ew = (const float*)d_in[2];
    p.W1 = (const float*)d_in[3];
    p.b1 = (const float*)d_in[4];
    p.W2 = (const float*)d_in[5];
    p.b2 = (const float*)d_in[6];
    p.out = (float*)d_out;

    p.N = in_sizes[0] / D;
    p.E = in_sizes[2];
    p.C = (p.N + CSZ - 1) / CSZ;
    p.B1n = (p.E + EPB - 1) / EPB;
    p.total = p.C * p.B1n;
    p.sb = (p.total + 255) / 256;
    p.gb = (p.N + 63) / 64;
    p.hb = (p.N + 7) / 8;

    char* w = (char*)d_ws;
    auto alloc = [&](size_t bytes) {
        void* r = (void*)w;
        w += (bytes + 255) & ~(size_t)255;
        return r;
    };
    p.bh       = (unsigned int*)alloc((size_t)p.total * 4);
    p.ebase    = (int*)alloc((size_t)p.total * 4);
    p.bsums    = (int*)alloc(1024 * 4);
    p.dinv     = (float*)alloc((size_t)p.N * 4);
    p.cnt      = (int*)alloc((size_t)p.N * 4);
    p.rowstart = (int*)alloc((size_t)p.N * 4);
    p.brec     = (int2*)alloc((size_t)p.E * 8);
    p.erec     = (int2*)alloc((size_t)p.E * 8);
    p.Hbuf     = (unsigned short*)alloc((size_t)p.N * D * 2);
    p.Abuf     = (unsigned short*)alloc((size_t)p.N * D * 2);
    p.Wt1      = (unsigned short*)alloc(128 * 128 * 2);
    p.Wt2      = (unsigned short*)alloc(128 * 128 * 2);

    k_f0<<<2 + p.B1n, 256, 0, stream>>>(p);
    k_f1<<<p.gb + p.sb, 256, 0, stream>>>(p);
    k_f2<<<p.sb, 256, 0, stream>>>(p);
    k_f3<<<p.B1n, 256, 0, stream>>>(p);
    k_f4<<<p.C, 256, 0, stream>>>(p);
    k_g5<<<p.gb, 256, 0, stream>>>(p);
    k_g6<<<p.hb, 256, 0, stream>>>(p);
}

// Round 7
// 202.508 us; speedup vs baseline: 1.2699x; 1.0086x over previous
//
#include <hip/hip_runtime.h>
#include <stdint.h>

#define D 128
#define EPB 4096   // edges per histogram/scatter block (R0-proven)
#define CSZ 128    // nodes per cluster (cluster = dst >> 7)

typedef __bf16 bf16x8 __attribute__((ext_vector_type(8)));
typedef float f32x4 __attribute__((ext_vector_type(4)));

__device__ inline float bf2f(unsigned short u) {
    return __uint_as_float((unsigned)u << 16);
}
__device__ inline unsigned short f2bf(float f) {
    unsigned u = __float_as_uint(f);
    return (unsigned short)((u + 0x7FFF + ((u >> 16) & 1)) >> 16);  // RNE
}

struct Params {
    const float* x; const int* ei; const float* ew;
    const float* W1; const float* b1; const float* W2; const float* b2;
    float* out;
    int N, E, C, B1n, total, gb, gb2, hb, sb;
    unsigned short *Wt1, *Wt2;
    unsigned int* bh; int* ebase; int* bsums;
    float* dinv; int* cnt; int* rowstart;
    int2* brec; int2* erec;
    unsigned short *Hbuf, *Abuf;
};

// ================= phase bodies (R0-verified, verbatim) =================

__device__ inline void dev_prep(int which, const Params& p) {
    const float* W = (which == 0) ? p.W1 : p.W2;
    unsigned short* Wt = (which == 0) ? p.Wt1 : p.Wt2;
    for (int i = threadIdx.x; i < 2048; i += 256) {
        int nn = i >> 4;
        int kc = (i & 15) << 3;
        ushort4 o0, o1;
        o0.x = f2bf(W[(kc + 0) * 128 + nn]); o0.y = f2bf(W[(kc + 1) * 128 + nn]);
        o0.z = f2bf(W[(kc + 2) * 128 + nn]); o0.w = f2bf(W[(kc + 3) * 128 + nn]);
        o1.x = f2bf(W[(kc + 4) * 128 + nn]); o1.y = f2bf(W[(kc + 5) * 128 + nn]);
        o1.z = f2bf(W[(kc + 6) * 128 + nn]); o1.w = f2bf(W[(kc + 7) * 128 + nn]);
        *(ushort4*)(Wt + nn * 128 + kc) = o0;
        *(ushort4*)(Wt + nn * 128 + kc + 4) = o1;
    }
}

__device__ inline void dev_hist(int b, const Params& p, unsigned int* hist) {
    for (int i = threadIdx.x; i < p.C; i += 256) hist[i] = 0;
    __syncthreads();
    const int base = b * EPB + threadIdx.x;
#pragma unroll
    for (int k = 0; k < EPB / 256; ++k) {
        int e = base + k * 256;
        if (e < p.E) atomicAdd(&hist[((unsigned)p.ei[p.E + e]) >> 7], 1u);
    }
    __syncthreads();
    for (int i = threadIdx.x; i < p.C; i += 256) p.bh[(size_t)b * p.C + i] = hist[i];
}

__device__ inline void dev_scanA(int blk, const Params& p, int* tmp) {
    const int tid = threadIdx.x;
    const int i = blk * 256 + tid;
    int v = 0;
    if (i < p.total) {
        int c = i / p.B1n;
        int b = i - c * p.B1n;
        v = (int)p.bh[(size_t)b * p.C + c];
    }
    tmp[tid] = v;
    __syncthreads();
    for (int off = 1; off < 256; off <<= 1) {
        int t = (tid >= off) ? tmp[tid - off] : 0;
        __syncthreads();
        tmp[tid] += t;
        __syncthreads();
    }
    if (i < p.total) p.ebase[i] = tmp[tid] - v;
    if (tid == 255) p.bsums[blk] = tmp[255];
}

__device__ inline void dev_scanB(int blk, const Params& p, int* sred) {
    const int tid = threadIdx.x;
    int v = (tid < blk) ? p.bsums[tid] : 0;
#pragma unroll
    for (int off = 32; off; off >>= 1) v += __shfl_down(v, off);
    if ((tid & 63) == 0) sred[tid >> 6] = v;
    __syncthreads();
    int tot = sred[0] + sred[1] + sred[2] + sred[3];
    int i = blk * 256 + tid;
    if (i < p.total) p.ebase[i] += tot;
}

__device__ inline void dev_scat(int b, const Params& p, unsigned int* cur) {
    for (int i = threadIdx.x; i < p.C; i += 256) cur[i] = 0;
    __syncthreads();
    const int base = b * EPB + threadIdx.x;
#pragma unroll
    for (int k = 0; k < EPB / 256; ++k) {
        int e = base + k * 256;
        if (e < p.E) {
            int s = p.ei[e];
            unsigned d = (unsigned)p.ei[p.E + e];
            float w = p.ew[e];
            int c = d >> 7;
            unsigned r = atomicAdd(&cur[c], 1u);
            int pos = p.ebase[c * p.B1n + b] + (int)r;
            p.brec[pos] = make_int2((int)((d << 16) | (unsigned)s), __float_as_int(w));
        }
    }
}

__device__ inline void dev_cbuild(int c, const Params& p, unsigned int* a) {
    unsigned int* hcnt = a;
    unsigned int* hdeg = a + CSZ;
    unsigned int* lsc  = a + 2 * CSZ;
    unsigned int* curs = a + 3 * CSZ;
    const int tid = threadIdx.x;
    const int cs = p.ebase[c * p.B1n];
    const int ce = (c + 1 < p.C) ? p.ebase[(c + 1) * p.B1n] : p.E;
    if (tid < CSZ) { hcnt[tid] = 0; hdeg[tid] = 0; }
    __syncthreads();
    for (int i = cs + tid; i < ce; i += 256) {
        int2 r = p.brec[i];
        int local = (int)(((unsigned)r.x) >> 16) & (CSZ - 1);
        atomicAdd(&hcnt[local], 1u);
        atomicAdd(&hdeg[local], (unsigned)(__int_as_float(r.y) * 16777216.0f));
    }
    __syncthreads();
    if (tid < CSZ) lsc[tid] = hcnt[tid];
    __syncthreads();
    for (int off = 1; off < CSZ; off <<= 1) {
        unsigned t = (tid < CSZ && tid >= off) ? lsc[tid - off] : 0u;
        __syncthreads();
        if (tid < CSZ) lsc[tid] += t;
        __syncthreads();
    }
    if (tid < CSZ) {
        unsigned excl = lsc[tid] - hcnt[tid];
        curs[tid] = excl;
        int node = c * CSZ + tid;
        if (node < p.N) {
            p.rowstart[node] = cs + (int)excl;
            p.cnt[node] = (int)hcnt[tid];
            float deg = 1.0f + (float)hdeg[tid] * (1.0f / 16777216.0f);
            p.dinv[node] = rsqrtf(deg);
        }
    }
    __syncthreads();
    for (int i = cs + tid; i < ce; i += 256) {
        int2 r = p.brec[i];
        int local = (int)(((unsigned)r.x) >> 16) & (CSZ - 1);
        unsigned rk = atomicAdd(&curs[local], 1u);
        p.erec[cs + (int)rk] = make_int2(r.x & 0xFFFF, r.y);   // (src, ew)
    }
}

// ---------------- MFMA GEMM body (R0-verified, verbatim): GEMM1 ----------------
template <bool IN_BF16>
__device__ inline void mfma_body(unsigned short* sE,
                                 const void* __restrict__ Xv,
                                 const unsigned short* __restrict__ Wt,
                                 unsigned short* __restrict__ H, int n, int blk) {
    const int tid = threadIdx.x;
    const int row0 = blk * 64;
    const int lane = tid & 63;
    const int wv = tid >> 6;
    const int qm = lane & 15;
    const int quad = lane >> 4;

    const int arow = row0 + wv * 16 + qm;
    const int ar = (arow < n) ? arow : (n - 1);

    f32x4 acc[8];
#pragma unroll
    for (int i = 0; i < 8; ++i) acc[i] = (f32x4){0.f, 0.f, 0.f, 0.f};

#pragma unroll
    for (int kb = 0; kb < 4; ++kb) {
        const int koff = kb * 32 + quad * 8;
        bf16x8 a;
        if (IN_BF16) {
            a = *(const bf16x8*)((const unsigned short*)Xv + (size_t)ar * 128 + koff);
        } else {
            const float* Xf = (const float*)Xv + (size_t)ar * 128 + koff;
            float4 v0 = *(const float4*)(Xf);
            float4 v1 = *(const float4*)(Xf + 4);
            union { bf16x8 v; ushort4 u[2]; } cv;
            cv.u[0].x = f2bf(v0.x); cv.u[0].y = f2bf(v0.y);
            cv.u[0].z = f2bf(v0.z); cv.u[0].w = f2bf(v0.w);
            cv.u[1].x = f2bf(v1.x); cv.u[1].y = f2bf(v1.y);
            cv.u[1].z = f2bf(v1.z); cv.u[1].w = f2bf(v1.w);
            a = cv.v;
        }
#pragma unroll
        for (int n0 = 0; n0 < 8; ++n0) {
            bf16x8 b = *(const bf16x8*)(Wt + (n0 * 16 + qm) * 128 + koff);
            acc[n0] = __builtin_amdgcn_mfma_f32_16x16x32_bf16(a, b, acc[n0], 0, 0, 0);
        }
    }

#pragma unroll
    for (int n0 = 0; n0 < 8; ++n0)
#pragma unroll
        for (int r = 0; r < 4; ++r)
            sE[(wv * 16 + quad * 4 + r) * 136 + n0 * 16 + qm] = f2bf(acc[n0][r]);
    __syncthreads();

    const int row_in = lane >> 2;
    const int c0 = (lane & 3) * 4;
    const int grow = row0 + wv * 16 + row_in;
    if (grow < n) {
#pragma unroll
        for (int j = 0; j < 4; ++j)
            *(int4*)(H + (size_t)grow * 128 + (c0 + j) * 8) =
                *(const int4*)(&sE[(wv * 16 + row_in) * 136 + (c0 + j) * 8]);
    }
}

// ---------------- gather one node's layer-1 row into LDS (body identical to R2) ----------------
__device__ inline void gather1_node(const Params& p, unsigned short* dst, int node, int lane8) {
    const ushort4* __restrict__ H4 = (const ushort4*)p.Hbuf;
    if (node < p.N) {
        const int start = p.rowstart[node];
        const int m = p.cnt[node];
        const float di = p.dinv[node];
        const ushort4* Hrow = H4 + (size_t)node * 32 + lane8 * 4;
        float acc[16];
#pragma unroll
        for (int q = 0; q < 4; ++q) {
            ushort4 h = Hrow[q];
            acc[q * 4 + 0] = di * bf2f(h.x);
            acc[q * 4 + 1] = di * bf2f(h.y);
            acc[q * 4 + 2] = di * bf2f(h.z);
            acc[q * 4 + 3] = di * bf2f(h.w);
        }
        int j = 0;
        for (; j + 2 <= m; j += 2) {
            int2 e0 = p.erec[start + j];
            int2 e1 = p.erec[start + j + 1];
            float w0 = p.dinv[e0.x] * __int_as_float(e0.y);
            float w1 = p.dinv[e1.x] * __int_as_float(e1.y);
            const ushort4* V0 = H4 + (size_t)e0.x * 32 + lane8 * 4;
            const ushort4* V1 = H4 + (size_t)e1.x * 32 + lane8 * 4;
#pragma unroll
            for (int q = 0; q < 4; ++q) {
                ushort4 v0 = V0[q], v1 = V1[q];
                acc[q * 4 + 0] += w0 * bf2f(v0.x) + w1 * bf2f(v1.x);
                acc[q * 4 + 1] += w0 * bf2f(v0.y) + w1 * bf2f(v1.y);
                acc[q * 4 + 2] += w0 * bf2f(v0.z) + w1 * bf2f(v1.z);
                acc[q * 4 + 3] += w0 * bf2f(v0.w) + w1 * bf2f(v1.w);
            }
        }
        if (j < m) {
            int2 e0 = p.erec[start + j];
            float w0 = p.dinv[e0.x] * __int_as_float(e0.y);
            const ushort4* V0 = H4 + (size_t)e0.x * 32 + lane8 * 4;
#pragma unroll
            for (int q = 0; q < 4; ++q) {
                ushort4 v0 = V0[q];
                acc[q * 4 + 0] += w0 * bf2f(v0.x);
                acc[q * 4 + 1] += w0 * bf2f(v0.y);
                acc[q * 4 + 2] += w0 * bf2f(v0.z);
                acc[q * 4 + 3] += w0 * bf2f(v0.w);
            }
        }
        const float* bb = p.b1 + lane8 * 16;
#pragma unroll
        for (int q = 0; q < 4; ++q) {
            ushort4 o;
            o.x = f2bf(fmaxf(bb[q * 4 + 0] + di * acc[q * 4 + 0], 0.f));
            o.y = f2bf(fmaxf(bb[q * 4 + 1] + di * acc[q * 4 + 1], 0.f));
            o.z = f2bf(fmaxf(bb[q * 4 + 2] + di * acc[q * 4 + 2], 0.f));
            o.w = f2bf(fmaxf(bb[q * 4 + 3] + di * acc[q * 4 + 3], 0.f));
            *(ushort4*)(dst + q * 4) = o;
        }
    } else {
        ushort4 z = {0, 0, 0, 0};
#pragma unroll
        for (int q = 0; q < 4; ++q) *(ushort4*)(dst + q * 4) = z;
    }
}

// ---------------- gather layer 2 (R6-verified, verbatim) ----------------
__device__ inline void gather2_body(const Params& p, const ushort4* __restrict__ H4,
                                    const float4* __restrict__ bias4,
                                    float4* __restrict__ OUT, int g) {
    const int lane = threadIdx.x & 31;
    const int node = g * 8 + (threadIdx.x >> 5);
    if (node >= p.N) return;
    const int start = p.rowstart[node];
    const int m = p.cnt[node];
    const float di = p.dinv[node];

    float4 b = bias4[lane];
    ushort4 h = H4[(size_t)node * 32 + lane];
    float ax = bf2f(h.x);
    float ay = bf2f(h.y);
    float az = bf2f(h.z);
    float aw = bf2f(h.w);

    int j = 0;
    for (; j + 4 <= m; j += 4) {
        const int base = start + j;
        int2 e0 = p.erec[base + 0], e1 = p.erec[base + 1];
        int2 e2 = p.erec[base + 2], e3 = p.erec[base + 3];
        float w0 = __int_as_float(e0.y);
        float w1 = __int_as_float(e1.y);
        float w2 = __int_as_float(e2.y);
        float w3 = __int_as_float(e3.y);
        ushort4 v0 = H4[(size_t)e0.x * 32 + lane];
        ushort4 v1 = H4[(size_t)e1.x * 32 + lane];
        ushort4 v2 = H4[(size_t)e2.x * 32 + lane];
        ushort4 v3 = H4[(size_t)e3.x * 32 + lane];
        ax += w0 * bf2f(v0.x); ay += w0 * bf2f(v0.y); az += w0 * bf2f(v0.z); aw += w0 * bf2f(v0.w);
        ax += w1 * bf2f(v1.x); ay += w1 * bf2f(v1.y); az += w1 * bf2f(v1.z); aw += w1 * bf2f(v1.w);
        ax += w2 * bf2f(v2.x); ay += w2 * bf2f(v2.y); az += w2 * bf2f(v2.z); aw += w2 * bf2f(v2.w);
        ax += w3 * bf2f(v3.x); ay += w3 * bf2f(v3.y); az += w3 * bf2f(v3.z); aw += w3 * bf2f(v3.w);
    }
    for (; j < m; ++j) {
        int2 er = p.erec[start + j];
        float w = __int_as_float(er.y);
        ushort4 v = H4[(size_t)er.x * 32 + lane];
        ax += w * bf2f(v.x); ay += w * bf2f(v.y); az += w * bf2f(v.z); aw += w * bf2f(v.w);
    }
    float4 o;
    o.x = b.x + di * ax; o.y = b.y + di * ay;
    o.z = b.z + di * az; o.w = b.w + di * aw;
    OUT[(size_t)node * 32 + lane] = o;
}

// ================= 7-kernel pipeline =================
__global__ __launch_bounds__(256, 4) void k_f0(Params p) {   // prep + hist
    __shared__ __align__(16) unsigned int hist[512];
    if (blockIdx.x < 2) dev_prep(blockIdx.x, p);
    else dev_hist(blockIdx.x - 2, p, hist);
}
__global__ __launch_bounds__(256, 4) void k_f1(Params p) {   // GEMM1 + scanA
    __shared__ __align__(16) char arena[64 * 136 * 2];
    if ((int)blockIdx.x < p.gb) mfma_body<false>((unsigned short*)arena, (const void*)p.x, p.Wt1, p.Hbuf, p.N, blockIdx.x);
    else dev_scanA(blockIdx.x - p.gb, p, (int*)arena);
}
__global__ __launch_bounds__(256) void k_f2(Params p) {      // scanB
    __shared__ int sred[4];
    dev_scanB(blockIdx.x, p, sred);
}
__global__ __launch_bounds__(256) void k_f3(Params p) {      // scatter -> brec
    __shared__ unsigned int cur[512];
    dev_scat(blockIdx.x, p, cur);
}
__global__ __launch_bounds__(256) void k_f4(Params p) {      // CSR build -> erec/dinv/cnt/rowstart
    __shared__ unsigned int a[4 * CSZ];
    dev_cbuild(blockIdx.x, p, a);
}
// fused gather1 + GEMM2, 32-row tile (2x grid for latency hiding) + dinv-fold epilogue
__global__ __launch_bounds__(256, 4) void k_g5(Params p) {
    __shared__ __align__(16) unsigned short sA[32 * 136];
    __shared__ __align__(16) unsigned short sE[32 * 136];
    const int row0 = blockIdx.x * 32;
    const int tid = threadIdx.x;

    // gather 32 nodes (8 lanes x 32 groups, single pass)
    gather1_node(p, sA + (tid >> 3) * 136 + (tid & 7) * 16, row0 + (tid >> 3), tid & 7);
    __syncthreads();

    const int lane = tid & 63;
    const int wv = tid >> 6;        // 0..3
    const int qm = lane & 15;
    const int quad = lane >> 4;
    const int rh = wv & 1;          // row half (16 rows)
    const int ch = wv >> 1;         // col half (64 cols)

    f32x4 acc[4];
#pragma unroll
    for (int i = 0; i < 4; ++i) acc[i] = (f32x4){0.f, 0.f, 0.f, 0.f};

#pragma unroll
    for (int kb = 0; kb < 4; ++kb) {
        const int koff = kb * 32 + quad * 8;
        bf16x8 a = *(const bf16x8*)(sA + (rh * 16 + qm) * 136 + koff);
#pragma unroll
        for (int n0 = 0; n0 < 4; ++n0) {
            bf16x8 b = *(const bf16x8*)(p.Wt2 + ((ch * 4 + n0) * 16 + qm) * 128 + koff);
            acc[n0] = __builtin_amdgcn_mfma_f32_16x16x32_bf16(a, b, acc[n0], 0, 0, 0);
        }
    }

    // per-C-row dinv (fold into H2s, fp32 before the single bf16 rounding)
    const int crow = rh * 16 + quad * 4;
    float di[4];
#pragma unroll
    for (int r = 0; r < 4; ++r) {
        int rr = row0 + crow + r;
        int rc = (rr < p.N) ? rr : (p.N - 1);
        di[r] = p.dinv[rc];
    }

#pragma unroll
    for (int n0 = 0; n0 < 4; ++n0)
#pragma unroll
        for (int r = 0; r < 4; ++r)
            sE[(crow + r) * 136 + ch * 64 + n0 * 16 + qm] = f2bf(acc[n0][r] * di[r]);
    __syncthreads();

    // write 32 rows x 128 cols: each thread 2 int4 chunks
    const int row_in = tid >> 3;          // 0..31
    const int c0 = (tid & 7) * 2;         // int4-chunk pair
    const int grow = row0 + row_in;
    if (grow < p.N) {
        *(int4*)(p.Abuf + (size_t)grow * 128 + (c0 + 0) * 8) =
            *(const int4*)(&sE[row_in * 136 + (c0 + 0) * 8]);
        *(int4*)(p.Abuf + (size_t)grow * 128 + (c0 + 1) * 8) =
            *(const int4*)(&sE[row_in * 136 + (c0 + 1) * 8]);
    }
}
__global__ __launch_bounds__(256) void k_g6(Params p) {      // gather2 -> out fp32
    gather2_body(p, (const ushort4*)p.Abuf, (const float4*)p.b2, (float4*)p.out, blockIdx.x);
}

extern "C" void kernel_launch(void* const* d_in, const int* in_sizes, int n_in,
                              void* d_out, int out_size, void* d_ws, size_t ws_size,
                              hipStream_t stream) {
    Params p;
    p.x  = (const float*)d_in[0];
    p.ei = (const int*)d_in[1];
    p.ew = (const float*)d_in[2];
    p.W1 = (const float*)d_in[3];
    p.b1 = (const float*)d_in[4];
    p.W2 = (const float*)d_in[5];
    p.b2 = (const float*)d_in[6];
    p.out = (float*)d_out;

    p.N = in_sizes[0] / D;
    p.E = in_sizes[2];
    p.C = (p.N + CSZ - 1) / CSZ;
    p.B1n = (p.E + EPB - 1) / EPB;
    p.total = p.C * p.B1n;
    p.sb = (p.total + 255) / 256;
    p.gb = (p.N + 63) / 64;
    p.gb2 = (p.N + 31) / 32;
    p.hb = (p.N + 7) / 8;

    char* w = (char*)d_ws;
    auto alloc = [&](size_t bytes) {
        void* r = (void*)w;
        w += (bytes + 255) & ~(size_t)255;
        return r;
    };
    p.bh       = (unsigned int*)alloc((size_t)p.total * 4);
    p.ebase    = (int*)alloc((size_t)p.total * 4);
    p.bsums    = (int*)alloc(1024 * 4);
    p.dinv     = (float*)alloc((size_t)p.N * 4);
    p.cnt      = (int*)alloc((size_t)p.N * 4);
    p.rowstart = (int*)alloc((size_t)p.N * 4);
    p.brec     = (int2*)alloc((size_t)p.E * 8);
    p.erec     = (int2*)alloc((size_t)p.E * 8);
    p.Hbuf     = (unsigned short*)alloc((size_t)p.N * D * 2);
    p.Abuf     = (unsigned short*)alloc((size_t)p.N * D * 2);
    p.Wt1      = (unsigned short*)alloc(128 * 128 * 2);
    p.Wt2      = (unsigned short*)alloc(128 * 128 * 2);

    k_f0<<<2 + p.B1n, 256, 0, stream>>>(p);
    k_f1<<<p.gb + p.sb, 256, 0, stream>>>(p);
    k_f2<<<p.sb, 256, 0, stream>>>(p);
    k_f3<<<p.B1n, 256, 0, stream>>>(p);
    k_f4<<<p.C, 256, 0, stream>>>(p);
    k_g5<<<p.gb2, 256, 0, stream>>>(p);
    k_g6<<<p.hb, 256, 0, stream>>>(p);
}

// Round 8
// 197.729 us; speedup vs baseline: 1.3006x; 1.0242x over previous
//
#include <hip/hip_runtime.h>
#include <stdint.h>

#define D 128
#define EPB 4096   // edges per histogram/scatter block (R0-proven)
#define CSZ 128    // nodes per cluster (cluster = dst >> 7)

typedef __bf16 bf16x8 __attribute__((ext_vector_type(8)));
typedef float f32x4 __attribute__((ext_vector_type(4)));

__device__ inline float bf2f(unsigned short u) {
    return __uint_as_float((unsigned)u << 16);
}
__device__ inline unsigned short f2bf(float f) {
    unsigned u = __float_as_uint(f);
    return (unsigned short)((u + 0x7FFF + ((u >> 16) & 1)) >> 16);  // RNE
}

struct Params {
    const float* x; const int* ei; const float* ew;
    const float* W1; const float* b1; const float* W2; const float* b2;
    float* out;
    int N, E, C, B1n, total, gb, gb2, hb16, sb;
    unsigned short *Wt1, *Wt2;
    unsigned int* bh; int* ebase; int* bsums;
    float* dinv; int* cnt; int* rowstart;
    int2* brec; int2* erec;
    unsigned short *Hbuf, *Abuf;
};

// ================= phase bodies (R0-verified, verbatim) =================

__device__ inline void dev_prep(int which, const Params& p) {
    const float* W = (which == 0) ? p.W1 : p.W2;
    unsigned short* Wt = (which == 0) ? p.Wt1 : p.Wt2;
    for (int i = threadIdx.x; i < 2048; i += 256) {
        int nn = i >> 4;
        int kc = (i & 15) << 3;
        ushort4 o0, o1;
        o0.x = f2bf(W[(kc + 0) * 128 + nn]); o0.y = f2bf(W[(kc + 1) * 128 + nn]);
        o0.z = f2bf(W[(kc + 2) * 128 + nn]); o0.w = f2bf(W[(kc + 3) * 128 + nn]);
        o1.x = f2bf(W[(kc + 4) * 128 + nn]); o1.y = f2bf(W[(kc + 5) * 128 + nn]);
        o1.z = f2bf(W[(kc + 6) * 128 + nn]); o1.w = f2bf(W[(kc + 7) * 128 + nn]);
        *(ushort4*)(Wt + nn * 128 + kc) = o0;
        *(ushort4*)(Wt + nn * 128 + kc + 4) = o1;
    }
}

__device__ inline void dev_hist(int b, const Params& p, unsigned int* hist) {
    for (int i = threadIdx.x; i < p.C; i += 256) hist[i] = 0;
    __syncthreads();
    const int base = b * EPB + threadIdx.x;
#pragma unroll
    for (int k = 0; k < EPB / 256; ++k) {
        int e = base + k * 256;
        if (e < p.E) atomicAdd(&hist[((unsigned)p.ei[p.E + e]) >> 7], 1u);
    }
    __syncthreads();
    for (int i = threadIdx.x; i < p.C; i += 256) p.bh[(size_t)b * p.C + i] = hist[i];
}

__device__ inline void dev_scanA(int blk, const Params& p, int* tmp) {
    const int tid = threadIdx.x;
    const int i = blk * 256 + tid;
    int v = 0;
    if (i < p.total) {
        int c = i / p.B1n;
        int b = i - c * p.B1n;
        v = (int)p.bh[(size_t)b * p.C + c];
    }
    tmp[tid] = v;
    __syncthreads();
    for (int off = 1; off < 256; off <<= 1) {
        int t = (tid >= off) ? tmp[tid - off] : 0;
        __syncthreads();
        tmp[tid] += t;
        __syncthreads();
    }
    if (i < p.total) p.ebase[i] = tmp[tid] - v;
    if (tid == 255) p.bsums[blk] = tmp[255];
}

__device__ inline void dev_scanB(int blk, const Params& p, int* sred) {
    const int tid = threadIdx.x;
    int v = (tid < blk) ? p.bsums[tid] : 0;
#pragma unroll
    for (int off = 32; off; off >>= 1) v += __shfl_down(v, off);
    if ((tid & 63) == 0) sred[tid >> 6] = v;
    __syncthreads();
    int tot = sred[0] + sred[1] + sred[2] + sred[3];
    int i = blk * 256 + tid;
    if (i < p.total) p.ebase[i] += tot;
}

__device__ inline void dev_scat(int b, const Params& p, unsigned int* cur) {
    for (int i = threadIdx.x; i < p.C; i += 256) cur[i] = 0;
    __syncthreads();
    const int base = b * EPB + threadIdx.x;
#pragma unroll
    for (int k = 0; k < EPB / 256; ++k) {
        int e = base + k * 256;
        if (e < p.E) {
            int s = p.ei[e];
            unsigned d = (unsigned)p.ei[p.E + e];
            float w = p.ew[e];
            int c = d >> 7;
            unsigned r = atomicAdd(&cur[c], 1u);
            int pos = p.ebase[c * p.B1n + b] + (int)r;
            p.brec[pos] = make_int2((int)((d << 16) | (unsigned)s), __float_as_int(w));
        }
    }
}

__device__ inline void dev_cbuild(int c, const Params& p, unsigned int* a) {
    unsigned int* hcnt = a;
    unsigned int* hdeg = a + CSZ;
    unsigned int* lsc  = a + 2 * CSZ;
    unsigned int* curs = a + 3 * CSZ;
    const int tid = threadIdx.x;
    const int cs = p.ebase[c * p.B1n];
    const int ce = (c + 1 < p.C) ? p.ebase[(c + 1) * p.B1n] : p.E;
    if (tid < CSZ) { hcnt[tid] = 0; hdeg[tid] = 0; }
    __syncthreads();
    for (int i = cs + tid; i < ce; i += 256) {
        int2 r = p.brec[i];
        int local = (int)(((unsigned)r.x) >> 16) & (CSZ - 1);
        atomicAdd(&hcnt[local], 1u);
        atomicAdd(&hdeg[local], (unsigned)(__int_as_float(r.y) * 16777216.0f));
    }
    __syncthreads();
    if (tid < CSZ) lsc[tid] = hcnt[tid];
    __syncthreads();
    for (int off = 1; off < CSZ; off <<= 1) {
        unsigned t = (tid < CSZ && tid >= off) ? lsc[tid - off] : 0u;
        __syncthreads();
        if (tid < CSZ) lsc[tid] += t;
        __syncthreads();
    }
    if (tid < CSZ) {
        unsigned excl = lsc[tid] - hcnt[tid];
        curs[tid] = excl;
        int node = c * CSZ + tid;
        if (node < p.N) {
            p.rowstart[node] = cs + (int)excl;
            p.cnt[node] = (int)hcnt[tid];
            float deg = 1.0f + (float)hdeg[tid] * (1.0f / 16777216.0f);
            p.dinv[node] = rsqrtf(deg);
        }
    }
    __syncthreads();
    for (int i = cs + tid; i < ce; i += 256) {
        int2 r = p.brec[i];
        int local = (int)(((unsigned)r.x) >> 16) & (CSZ - 1);
        unsigned rk = atomicAdd(&curs[local], 1u);
        p.erec[cs + (int)rk] = make_int2(r.x & 0xFFFF, r.y);   // (src, ew)
    }
}

// ---------------- MFMA GEMM body (R0-verified, verbatim): GEMM1 ----------------
template <bool IN_BF16>
__device__ inline void mfma_body(unsigned short* sE,
                                 const void* __restrict__ Xv,
                                 const unsigned short* __restrict__ Wt,
                                 unsigned short* __restrict__ H, int n, int blk) {
    const int tid = threadIdx.x;
    const int row0 = blk * 64;
    const int lane = tid & 63;
    const int wv = tid >> 6;
    const int qm = lane & 15;
    const int quad = lane >> 4;

    const int arow = row0 + wv * 16 + qm;
    const int ar = (arow < n) ? arow : (n - 1);

    f32x4 acc[8];
#pragma unroll
    for (int i = 0; i < 8; ++i) acc[i] = (f32x4){0.f, 0.f, 0.f, 0.f};

#pragma unroll
    for (int kb = 0; kb < 4; ++kb) {
        const int koff = kb * 32 + quad * 8;
        bf16x8 a;
        if (IN_BF16) {
            a = *(const bf16x8*)((const unsigned short*)Xv + (size_t)ar * 128 + koff);
        } else {
            const float* Xf = (const float*)Xv + (size_t)ar * 128 + koff;
            float4 v0 = *(const float4*)(Xf);
            float4 v1 = *(const float4*)(Xf + 4);
            union { bf16x8 v; ushort4 u[2]; } cv;
            cv.u[0].x = f2bf(v0.x); cv.u[0].y = f2bf(v0.y);
            cv.u[0].z = f2bf(v0.z); cv.u[0].w = f2bf(v0.w);
            cv.u[1].x = f2bf(v1.x); cv.u[1].y = f2bf(v1.y);
            cv.u[1].z = f2bf(v1.z); cv.u[1].w = f2bf(v1.w);
            a = cv.v;
        }
#pragma unroll
        for (int n0 = 0; n0 < 8; ++n0) {
            bf16x8 b = *(const bf16x8*)(Wt + (n0 * 16 + qm) * 128 + koff);
            acc[n0] = __builtin_amdgcn_mfma_f32_16x16x32_bf16(a, b, acc[n0], 0, 0, 0);
        }
    }

#pragma unroll
    for (int n0 = 0; n0 < 8; ++n0)
#pragma unroll
        for (int r = 0; r < 4; ++r)
            sE[(wv * 16 + quad * 4 + r) * 136 + n0 * 16 + qm] = f2bf(acc[n0][r]);
    __syncthreads();

    const int row_in = lane >> 2;
    const int c0 = (lane & 3) * 4;
    const int grow = row0 + wv * 16 + row_in;
    if (grow < n) {
#pragma unroll
        for (int j = 0; j < 4; ++j)
            *(int4*)(H + (size_t)grow * 128 + (c0 + j) * 8) =
                *(const int4*)(&sE[(wv * 16 + row_in) * 136 + (c0 + j) * 8]);
    }
}

// ---------------- gather layer-1, 16 lanes/node, int4 row loads ----------------
// Writes one node's bf16 A-row (bias+ReLU applied) into LDS (16B per lane).
__device__ inline void gather1_node16(const Params& p, unsigned short* dst, int node, int lane) {
    const int4* __restrict__ H16 = (const int4*)p.Hbuf;   // 16 int4 per 128-col bf16 row
    union U8 { int4 v; unsigned short u[8]; };
    if (node < p.N) {
        const int start = p.rowstart[node];
        const int m = p.cnt[node];
        const float di = p.dinv[node];
        U8 s; s.v = H16[(size_t)node * 16 + lane];
        float acc[8];
#pragma unroll
        for (int q = 0; q < 8; ++q) acc[q] = di * bf2f(s.u[q]);

        const int2* __restrict__ er = p.erec + start;
        int j = 0;
        for (; j + 4 <= m; j += 4) {
            int2 e0 = er[j], e1 = er[j + 1], e2 = er[j + 2], e3 = er[j + 3];
            U8 v0, v1, v2, v3;
            v0.v = H16[(size_t)e0.x * 16 + lane];
            v1.v = H16[(size_t)e1.x * 16 + lane];
            v2.v = H16[(size_t)e2.x * 16 + lane];
            v3.v = H16[(size_t)e3.x * 16 + lane];
            float w0 = p.dinv[e0.x] * __int_as_float(e0.y);
            float w1 = p.dinv[e1.x] * __int_as_float(e1.y);
            float w2 = p.dinv[e2.x] * __int_as_float(e2.y);
            float w3 = p.dinv[e3.x] * __int_as_float(e3.y);
#pragma unroll
            for (int q = 0; q < 8; ++q)
                acc[q] += w0 * bf2f(v0.u[q]) + w1 * bf2f(v1.u[q]) +
                          w2 * bf2f(v2.u[q]) + w3 * bf2f(v3.u[q]);
        }
        for (; j < m; ++j) {
            int2 e0 = er[j];
            U8 v0; v0.v = H16[(size_t)e0.x * 16 + lane];
            float w0 = p.dinv[e0.x] * __int_as_float(e0.y);
#pragma unroll
            for (int q = 0; q < 8; ++q) acc[q] += w0 * bf2f(v0.u[q]);
        }
        const float4 b0 = *(const float4*)(p.b1 + lane * 8);
        const float4 b1v = *(const float4*)(p.b1 + lane * 8 + 4);
        const float bb[8] = {b0.x, b0.y, b0.z, b0.w, b1v.x, b1v.y, b1v.z, b1v.w};
        U8 o;
#pragma unroll
        for (int q = 0; q < 8; ++q) o.u[q] = f2bf(fmaxf(bb[q] + di * acc[q], 0.f));
        *(int4*)dst = o.v;
    } else {
        *(int4*)dst = (int4){0, 0, 0, 0};
    }
}

// ---------------- gather layer 2, 16 lanes/node, int4 row loads (R3-verified shape) ----------------
// H2s rows pre-scaled by dinv (folded into fused GEMM2 epilogue) -> no per-edge dinv load.
__device__ inline void gather2_body16(const Params& p, const int4* __restrict__ H16,
                                      const float* __restrict__ bias,
                                      float4* __restrict__ OUT, int g) {
    const int lane = threadIdx.x & 15;
    const int node = g * 16 + (threadIdx.x >> 4);
    if (node >= p.N) return;
    const int start = p.rowstart[node];
    const int m = p.cnt[node];
    const float di = p.dinv[node];

    union U8 { int4 v; unsigned short u[8]; };
    U8 s; s.v = H16[(size_t)node * 16 + lane];
    float acc[8];
#pragma unroll
    for (int q = 0; q < 8; ++q) acc[q] = bf2f(s.u[q]);

    const int2* __restrict__ er = p.erec + start;
    int j = 0;
    for (; j + 4 <= m; j += 4) {
        int2 e0 = er[j], e1 = er[j + 1], e2 = er[j + 2], e3 = er[j + 3];
        U8 v0, v1, v2, v3;
        v0.v = H16[(size_t)e0.x * 16 + lane];
        v1.v = H16[(size_t)e1.x * 16 + lane];
        v2.v = H16[(size_t)e2.x * 16 + lane];
        v3.v = H16[(size_t)e3.x * 16 + lane];
        float w0 = __int_as_float(e0.y), w1 = __int_as_float(e1.y);
        float w2 = __int_as_float(e2.y), w3 = __int_as_float(e3.y);
#pragma unroll
        for (int q = 0; q < 8; ++q)
            acc[q] += w0 * bf2f(v0.u[q]) + w1 * bf2f(v1.u[q]) +
                      w2 * bf2f(v2.u[q]) + w3 * bf2f(v3.u[q]);
    }
    for (; j < m; ++j) {
        int2 e0 = er[j];
        U8 v0; v0.v = H16[(size_t)e0.x * 16 + lane];
        float w0 = __int_as_float(e0.y);
#pragma unroll
        for (int q = 0; q < 8; ++q) acc[q] += w0 * bf2f(v0.u[q]);
    }

    const float4 b0 = *(const float4*)(bias + lane * 8);
    const float4 b1v = *(const float4*)(bias + lane * 8 + 4);
    float4 f0, f1;
    f0.x = b0.x + di * acc[0]; f0.y = b0.y + di * acc[1];
    f0.z = b0.z + di * acc[2]; f0.w = b0.w + di * acc[3];
    f1.x = b1v.x + di * acc[4]; f1.y = b1v.y + di * acc[5];
    f1.z = b1v.z + di * acc[6]; f1.w = b1v.w + di * acc[7];
    OUT[(size_t)node * 32 + lane * 2] = f0;
    OUT[(size_t)node * 32 + lane * 2 + 1] = f1;
}

// ================= 7-kernel pipeline =================
__global__ __launch_bounds__(256, 4) void k_f0(Params p) {   // prep + hist
    __shared__ __align__(16) unsigned int hist[512];
    if (blockIdx.x < 2) dev_prep(blockIdx.x, p);
    else dev_hist(blockIdx.x - 2, p, hist);
}
__global__ __launch_bounds__(256, 4) void k_f1(Params p) {   // GEMM1 + scanA
    __shared__ __align__(16) char arena[64 * 136 * 2];
    if ((int)blockIdx.x < p.gb) mfma_body<false>((unsigned short*)arena, (const void*)p.x, p.Wt1, p.Hbuf, p.N, blockIdx.x);
    else dev_scanA(blockIdx.x - p.gb, p, (int*)arena);
}
__global__ __launch_bounds__(256) void k_f2(Params p) {      // scanB
    __shared__ int sred[4];
    dev_scanB(blockIdx.x, p, sred);
}
__global__ __launch_bounds__(256) void k_f3(Params p) {      // scatter -> brec
    __shared__ unsigned int cur[512];
    dev_scat(blockIdx.x, p, cur);
}
__global__ __launch_bounds__(256) void k_f4(Params p) {      // CSR build -> erec/dinv/cnt/rowstart
    __shared__ unsigned int a[4 * CSZ];
    dev_cbuild(blockIdx.x, p, a);
}
// fused gather1 + GEMM2, 32-row tile, 16-lane gather + dinv-fold epilogue
__global__ __launch_bounds__(256, 4) void k_g5(Params p) {
    __shared__ __align__(16) unsigned short sA[32 * 136];
    __shared__ __align__(16) unsigned short sE[32 * 136];
    const int row0 = blockIdx.x * 32;
    const int tid = threadIdx.x;

    // gather 32 nodes: 16 lanes/node, 16 nodes/pass, 2 passes
    const int lane16 = tid & 15;
    const int grp16 = tid >> 4;   // 0..15
#pragma unroll
    for (int pass = 0; pass < 2; ++pass) {
        const int local = pass * 16 + grp16;
        gather1_node16(p, sA + local * 136 + lane16 * 8, row0 + local, lane16);
    }
    __syncthreads();

    const int lane = tid & 63;
    const int wv = tid >> 6;        // 0..3
    const int qm = lane & 15;
    const int quad = lane >> 4;
    const int rh = wv & 1;          // row half (16 rows)
    const int ch = wv >> 1;         // col half (64 cols)

    f32x4 acc[4];
#pragma unroll
    for (int i = 0; i < 4; ++i) acc[i] = (f32x4){0.f, 0.f, 0.f, 0.f};

#pragma unroll
    for (int kb = 0; kb < 4; ++kb) {
        const int koff = kb * 32 + quad * 8;
        bf16x8 a = *(const bf16x8*)(sA + (rh * 16 + qm) * 136 + koff);
#pragma unroll
        for (int n0 = 0; n0 < 4; ++n0) {
            bf16x8 b = *(const bf16x8*)(p.Wt2 + ((ch * 4 + n0) * 16 + qm) * 128 + koff);
            acc[n0] = __builtin_amdgcn_mfma_f32_16x16x32_bf16(a, b, acc[n0], 0, 0, 0);
        }
    }

    // per-C-row dinv (fold into H2s, fp32 before the single bf16 rounding)
    const int crow = rh * 16 + quad * 4;
    float di[4];
#pragma unroll
    for (int r = 0; r < 4; ++r) {
        int rr = row0 + crow + r;
        int rc = (rr < p.N) ? rr : (p.N - 1);
        di[r] = p.dinv[rc];
    }

#pragma unroll
    for (int n0 = 0; n0 < 4; ++n0)
#pragma unroll
        for (int r = 0; r < 4; ++r)
            sE[(crow + r) * 136 + ch * 64 + n0 * 16 + qm] = f2bf(acc[n0][r] * di[r]);
    __syncthreads();

    // write 32 rows x 128 cols: each thread 2 int4 chunks
    const int row_in = tid >> 3;          // 0..31
    const int c0 = (tid & 7) * 2;         // int4-chunk pair
    const int grow = row0 + row_in;
    if (grow < p.N) {
        *(int4*)(p.Abuf + (size_t)grow * 128 + (c0 + 0) * 8) =
            *(const int4*)(&sE[row_in * 136 + (c0 + 0) * 8]);
        *(int4*)(p.Abuf + (size_t)grow * 128 + (c0 + 1) * 8) =
            *(const int4*)(&sE[row_in * 136 + (c0 + 1) * 8]);
    }
}
__global__ __launch_bounds__(256) void k_g6(Params p) {      // gather2 -> out fp32
    gather2_body16(p, (const int4*)p.Abuf, p.b2, (float4*)p.out, blockIdx.x);
}

extern "C" void kernel_launch(void* const* d_in, const int* in_sizes, int n_in,
                              void* d_out, int out_size, void* d_ws, size_t ws_size,
                              hipStream_t stream) {
    Params p;
    p.x  = (const float*)d_in[0];
    p.ei = (const int*)d_in[1];
    p.ew = (const float*)d_in[2];
    p.W1 = (const float*)d_in[3];
    p.b1 = (const float*)d_in[4];
    p.W2 = (const float*)d_in[5];
    p.b2 = (const float*)d_in[6];
    p.out = (float*)d_out;

    p.N = in_sizes[0] / D;
    p.E = in_sizes[2];
    p.C = (p.N + CSZ - 1) / CSZ;
    p.B1n = (p.E + EPB - 1) / EPB;
    p.total = p.C * p.B1n;
    p.sb = (p.total + 255) / 256;
    p.gb = (p.N + 63) / 64;
    p.gb2 = (p.N + 31) / 32;
    p.hb16 = (p.N + 15) / 16;

    char* w = (char*)d_ws;
    auto alloc = [&](size_t bytes) {
        void* r = (void*)w;
        w += (bytes + 255) & ~(size_t)255;
        return r;
    };
    p.bh       = (unsigned int*)alloc((size_t)p.total * 4);
    p.ebase    = (int*)alloc((size_t)p.total * 4);
    p.bsums    = (int*)alloc(1024 * 4);
    p.dinv     = (float*)alloc((size_t)p.N * 4);
    p.cnt      = (int*)alloc((size_t)p.N * 4);
    p.rowstart = (int*)alloc((size_t)p.N * 4);
    p.brec     = (int2*)alloc((size_t)p.E * 8);
    p.erec     = (int2*)alloc((size_t)p.E * 8);
    p.Hbuf     = (unsigned short*)alloc((size_t)p.N * D * 2);
    p.Abuf     = (unsigned short*)alloc((size_t)p.N * D * 2);
    p.Wt1      = (unsigned short*)alloc(128 * 128 * 2);
    p.Wt2      = (unsigned short*)alloc(128 * 128 * 2);

    k_f0<<<2 + p.B1n, 256, 0, stream>>>(p);
    k_f1<<<p.gb + p.sb, 256, 0, stream>>>(p);
    k_f2<<<p.sb, 256, 0, stream>>>(p);
    k_f3<<<p.B1n, 256, 0, stream>>>(p);
    k_f4<<<p.C, 256, 0, stream>>>(p);
    k_g5<<<p.gb2, 256, 0, stream>>>(p);
    k_g6<<<p.hb16, 256, 0, stream>>>(p);
}